// Round 4
// baseline (1543.249 us; speedup 1.0000x reference)
//
#include <hip/hip_runtime.h>
#include <hip/hip_bf16.h>

#define BB 64
#define LLEN 512
#define HH 400
#define L1 513
#define TT 32832      // BB*L1
#define NE 768        // enh(256)|enm(256)|elh(128)|elm(128)
#define KP 16640      // 16384 bilinear + 128 Wl + 128 Wr (phase-permuted)
#define PHW 4160      // per-phase k' width: 130 d-slices * 32

typedef __attribute__((ext_vector_type(4))) float f32x4;
typedef __attribute__((ext_vector_type(8))) short bf16x8;
typedef unsigned int u32;
typedef __attribute__((address_space(1))) const u32* gptr_t;
typedef __attribute__((address_space(3))) u32* sptr_t;

// round-to-nearest-even f32 -> bf16 (finite inputs)
__device__ inline unsigned short f2bf(float x){
  unsigned u = __float_as_uint(x);
  unsigned r = (u + 0x7fffu + ((u >> 16) & 1u)) >> 16;
  return (unsigned short)r;
}
// packed RNE f32x2 -> bf16x2 in one instruction (lo = a, hi = b)
__device__ inline unsigned cvtpk(float a, float b){
  unsigned r;
  asm("v_cvt_pk_bf16_f32 %0, %1, %2" : "=v"(r) : "v"(a), "v"(b));
  return r;
}
__device__ inline float bf2f(unsigned short h){
  return __uint_as_float(((unsigned)h) << 16);
}

// ---------------- init: labels1 output, gold gather idx, label buf, zero nll ----
__global__ __launch_bounds__(256) void k_init(const int* eh, const int* el, float* out,
                                              int* idx, int* labbuf){
  int t = blockIdx.x*256 + threadIdx.x;
  if (t < TT){
    int b = t / L1, m = t - b*L1;
    int lab = m ? el[b*LLEN + m - 1] : 0;
    int hd  = m ? eh[b*LLEN + m - 1] : 0;
    out[65536 + t] = (float)lab;
    labbuf[t] = lab;
    idx[t] = b*L1 + hd;
  }
  if (blockIdx.x == 0 && threadIdx.x < 2) out[98368 + threadIdx.x] = 0.f;
}

// ---------------- build concatenated encoder weights ----------------
__global__ __launch_bounds__(256) void k_wcat(const float* Wenh,const float* benh,
    const float* Wenm,const float* benm,const float* Welh,const float* belh,
    const float* Welm,const float* belm,float* Wcat,float* bcat){
  int g = blockIdx.x*256 + threadIdx.x;
  if (g < HH*NE){
    int k = g / NE, n = g - k*NE;
    float v;
    if (n < 256) v = Wenh[k*256 + n];
    else if (n < 512) v = Wenm[k*256 + n - 256];
    else if (n < 640) v = Welh[k*128 + n - 512];
    else v = Welm[k*128 + n - 640];
    Wcat[g] = v;
  }
  if (g < NE){
    float v;
    if (g < 256) v = benh[g];
    else if (g < 512) v = benm[g - 256];
    else if (g < 640) v = belh[g - 512];
    else v = belm[g - 640];
    bcat[g] = v;
  }
}

// ------------- build WtTp[n][k'] bf16, K phase-permuted: k' = p*4160 + d*32 + j,
// (p,d,j): d<128 -> U[n][d][32p+j]; d==128 -> Wl[n][32p+j]; d==129 -> Wr[n][32p+j]
__global__ __launch_bounds__(256) void k_wtt(const float* lblU, const float* Wl,
    const float* Wr, unsigned short* WtTp){
  int n = blockIdx.y;
  int kp = blockIdx.x*256 + threadIdx.x;
  if (kp >= KP) return;
  int p = kp / PHW; int q2 = kp - p*PHW; int dd = q2 >> 5; int j = q2 & 31; int e = p*32 + j;
  float v;
  if (dd < 128) v = lblU[(size_t)n*16384 + dd*128 + e];
  else if (dd == 128) v = Wl[n*128 + e];
  else v = Wr[n*128 + e];
  WtTp[(size_t)n*KP + kp] = f2bf(v);
}

#define INNER8(AS, BS) \
  _Pragma("unroll") \
  for (int kk = 0; kk < 8; kk++){ \
    float4 a0 = *(const float4*)&AS[kk][ty*8]; \
    float4 a1 = *(const float4*)&AS[kk][ty*8+4]; \
    float4 b0 = *(const float4*)&BS[kk][tx*8]; \
    float4 b1 = *(const float4*)&BS[kk][tx*8+4]; \
    float avv[8] = {a0.x,a0.y,a0.z,a0.w,a1.x,a1.y,a1.z,a1.w}; \
    float bvv[8] = {b0.x,b0.y,b0.z,b0.w,b1.x,b1.y,b1.z,b1.w}; \
    _Pragma("unroll") \
    for (int ii = 0; ii < 8; ii++) \
      _Pragma("unroll") \
      for (int jj = 0; jj < 8; jj++) \
        c_[ii][jj] += avv[ii]*bvv[jj]; \
  }

// ---------------- K1: E = elu([sentinel;mb] @ Wcat + bcat), fp32 128x128x8 tile ----
__global__ __launch_bounds__(256) void k_enc(const float* mb, const float* sent,
    const float* Wcat, const float* bcat, float* E){
  __shared__ float As[8][132];
  __shared__ float Bs[8][132];
  int tid = threadIdx.x, tx = tid & 15, ty = tid >> 4;
  int Mb = blockIdx.x * 128, n0 = blockIdx.y * 128;
  int ar = tid >> 1, akc = (tid & 1) * 4;
  int row = Mb + ar;
  bool aval = row < TT;
  const float* ap = sent;
  if (aval){
    int br = row / L1, mr = row - br*L1;
    if (mr) ap = mb + (size_t)(br*LLEN + mr - 1)*HH;
  }
  int bkr = tid >> 5, bnc = (tid & 31) * 4;
  float c_[8][8] = {};
  for (int k0 = 0; k0 < HH; k0 += 8){
    __syncthreads();
    float4 av = make_float4(0.f,0.f,0.f,0.f);
    if (aval) av = *(const float4*)(ap + k0 + akc);
    As[akc+0][ar] = av.x; As[akc+1][ar] = av.y; As[akc+2][ar] = av.z; As[akc+3][ar] = av.w;
    *(float4*)&Bs[bkr][bnc] = *(const float4*)(Wcat + (size_t)(k0 + bkr)*NE + n0 + bnc);
    __syncthreads();
    INNER8(As, Bs)
  }
  #pragma unroll
  for (int i = 0; i < 8; i++){
    int rr = Mb + ty*8 + i;
    if (rr < TT){
      float4 o0, o1;
      float t0v;
      t0v = c_[i][0] + bcat[n0+tx*8+0]; o0.x = t0v > 0.f ? t0v : expm1f(t0v);
      t0v = c_[i][1] + bcat[n0+tx*8+1]; o0.y = t0v > 0.f ? t0v : expm1f(t0v);
      t0v = c_[i][2] + bcat[n0+tx*8+2]; o0.z = t0v > 0.f ? t0v : expm1f(t0v);
      t0v = c_[i][3] + bcat[n0+tx*8+3]; o0.w = t0v > 0.f ? t0v : expm1f(t0v);
      t0v = c_[i][4] + bcat[n0+tx*8+4]; o1.x = t0v > 0.f ? t0v : expm1f(t0v);
      t0v = c_[i][5] + bcat[n0+tx*8+5]; o1.y = t0v > 0.f ? t0v : expm1f(t0v);
      t0v = c_[i][6] + bcat[n0+tx*8+6]; o1.z = t0v > 0.f ? t0v : expm1f(t0v);
      t0v = c_[i][7] + bcat[n0+tx*8+7]; o1.w = t0v > 0.f ? t0v : expm1f(t0v);
      *(float4*)&E[(size_t)rr*NE + n0 + tx*8] = o0;
      *(float4*)&E[(size_t)rr*NE + n0 + tx*8 + 4] = o1;
    }
  }
}

// ---------------- K2: T1 = enh @ ba_U ----------------
__global__ __launch_bounds__(256) void k_t1(const float* E, const float* baU, float* T1){
  __shared__ float As[8][132];
  __shared__ float Bs[8][132];
  int tid = threadIdx.x, tx = tid & 15, ty = tid >> 4;
  int Mb = blockIdx.x * 128, n0 = blockIdx.y * 128;
  int ar = tid >> 1, akc = (tid & 1) * 4;
  int row = Mb + ar;
  bool aval = row < TT;
  const float* ap = E + (size_t)(aval ? row : 0)*NE;
  int bkr = tid >> 5, bnc = (tid & 31) * 4;
  float c_[8][8] = {};
  for (int k0 = 0; k0 < 256; k0 += 8){
    __syncthreads();
    float4 av = make_float4(0.f,0.f,0.f,0.f);
    if (aval) av = *(const float4*)(ap + k0 + akc);
    As[akc+0][ar] = av.x; As[akc+1][ar] = av.y; As[akc+2][ar] = av.z; As[akc+3][ar] = av.w;
    *(float4*)&Bs[bkr][bnc] = *(const float4*)(baU + (size_t)(k0 + bkr)*256 + n0 + bnc);
    __syncthreads();
    INNER8(As, Bs)
  }
  #pragma unroll
  for (int i = 0; i < 8; i++){
    int rr = Mb + ty*8 + i;
    if (rr < TT){
      float4 o0 = {c_[i][0],c_[i][1],c_[i][2],c_[i][3]};
      float4 o1 = {c_[i][4],c_[i][5],c_[i][6],c_[i][7]};
      *(float4*)&T1[(size_t)rr*256 + n0 + tx*8] = o0;
      *(float4*)&T1[(size_t)rr*256 + n0 + tx*8 + 4] = o1;
    }
  }
}

// ---------------- K2b: dvec = enh@ba_Wd + ba_b ; evec = enm@ba_We ----------------
__global__ __launch_bounds__(256) void k_vecs(const float* E, const float* Wd,
    const float* We, const float* bab, float* dvec, float* evec){
  int w = threadIdx.x >> 6, lane = threadIdx.x & 63;
  int t = blockIdx.x*4 + w;
  const float* enh = E + (size_t)t*NE;
  const float* enm = enh + 256;
  float sd = 0.f, se = 0.f;
  for (int l = lane; l < 256; l += 64){ sd += enh[l]*Wd[l]; se += enm[l]*We[l]; }
  for (int o = 1; o < 64; o <<= 1){ sd += __shfl_xor(sd, o, 64); se += __shfl_xor(se, o, 64); }
  if (lane == 0){ dvec[t] = sd + bab[0]; evec[t] = se; }
}

// ---------------- K3a: S[b,h,m] = T1[b,h,:]·enm[b,m,:] + dvec[h] + evec[m] ----------
__global__ __launch_bounds__(256) void k_ns(const float* T1, const float* E,
    const float* dvec, const float* evec, float* S){
  __shared__ float As[8][132];
  __shared__ float Bs[8][132];
  int tid = threadIdx.x, tx = tid & 15, ty = tid >> 4;
  int b = blockIdx.y;
  int tm = blockIdx.x / 5, tn = blockIdx.x - tm*5;
  int Mb = tm*128, n0 = tn*128;
  int ar = tid >> 1, akc = (tid & 1) * 4;
  int hrow = Mb + ar; bool aval = hrow < L1;
  const float* ap = T1 + ((size_t)b*L1 + (aval ? hrow : 0))*256;
  int mrow = n0 + ar; bool bval = mrow < L1;
  const float* bp = E + ((size_t)b*L1 + (bval ? mrow : 0))*NE + 256;
  float c_[8][8] = {};
  for (int k0 = 0; k0 < 256; k0 += 8){
    __syncthreads();
    float4 av = make_float4(0.f,0.f,0.f,0.f);
    float4 bv2 = make_float4(0.f,0.f,0.f,0.f);
    if (aval) av = *(const float4*)(ap + k0 + akc);
    if (bval) bv2 = *(const float4*)(bp + k0 + akc);
    As[akc+0][ar] = av.x; As[akc+1][ar] = av.y; As[akc+2][ar] = av.z; As[akc+3][ar] = av.w;
    Bs[akc+0][ar] = bv2.x; Bs[akc+1][ar] = bv2.y; Bs[akc+2][ar] = bv2.z; Bs[akc+3][ar] = bv2.w;
    __syncthreads();
    INNER8(As, Bs)
  }
  float dr[8], er[8];
  #pragma unroll
  for (int i = 0; i < 8; i++){ int h = Mb + ty*8 + i; dr[i] = (h < L1) ? dvec[b*L1 + h] : 0.f; }
  #pragma unroll
  for (int j = 0; j < 8; j++){ int m = n0 + tx*8 + j; er[j] = (m < L1) ? evec[b*L1 + m] : 0.f; }
  float* Sb = S + (size_t)b*L1*L1;
  #pragma unroll
  for (int i = 0; i < 8; i++){
    int h = Mb + ty*8 + i;
    if (h < L1){
      #pragma unroll
      for (int j = 0; j < 8; j++){
        int m = n0 + tx*8 + j;
        if (m < L1) Sb[(size_t)h*L1 + m] = c_[i][j] + dr[i] + er[j];
      }
    }
  }
}

// --------- K3b: per-column log-softmax(gold) + node_nll + argmax decode -----------
__global__ __launch_bounds__(256) void k_nodecol(const float* S, const int* eh,
    const int* mask, float* out, int* idx){
  int b = blockIdx.y, mt = blockIdx.x;
  __shared__ float msk[L1];
  __shared__ float rM[8][32], rS[8][32], rG[8][32], rB[8][32];
  __shared__ int rH[8][32];
  __shared__ float npart[32];
  int tid = threadIdx.x; int c = tid & 31, r = tid >> 5;
  for (int h = tid; h < L1; h += 256) msk[h] = h ? (float)mask[b*LLEN + h - 1] : 0.f;
  __syncthreads();
  int m = mt*32 + c; bool valid = m < L1; int mc = valid ? m : (L1-1);
  float maskm = msk[mc];
  int gold = 0; if (valid && m) gold = eh[b*LLEN + m - 1];
  const float* Sb = S + (size_t)b*L1*L1;
  float Mx = -3.4e38f, Sm = 0.f, G = 0.f, Bv = -3.4e38f; int Bh = 0;
  for (int h = r; h < L1; h += 8){
    float s = Sb[(size_t)h*L1 + mc];
    float adj = s + ((msk[h] + maskm) > 1.5f ? 0.69314718055994531f : 0.f);
    float nm = fmaxf(Mx, adj);
    Sm = Sm * expf(Mx - nm) + expf(adj - nm);
    Mx = nm;
    if (h == gold) G = adj;
    float dv = (h == m) ? -3.4e38f : (s + (msk[h] > 0.5f ? 0.f : -1e8f));
    if (dv > Bv){ Bv = dv; Bh = h; }
  }
  rM[r][c] = Mx; rS[r][c] = Sm; rG[r][c] = G; rB[r][c] = Bv; rH[r][c] = Bh;
  __syncthreads();
  if (r == 0){
    float M0 = rM[0][c], S0 = rS[0][c], G0 = rG[0][c], B0 = rB[0][c]; int H0 = rH[0][c];
    for (int rr = 1; rr < 8; rr++){
      float m2 = rM[rr][c], s2 = rS[rr][c];
      float nm = fmaxf(M0, m2);
      S0 = S0*expf(M0 - nm) + s2*expf(m2 - nm); M0 = nm;
      G0 += rG[rr][c];
      float b2 = rB[rr][c]; int h2 = rH[rr][c];
      if (b2 > B0 || (b2 == B0 && h2 < H0)){ B0 = b2; H0 = h2; }
    }
    float nll = 0.f;
    if (valid && m >= 1) nll = (M0 + logf(S0)) - G0;
    npart[c] = nll;
    if (valid){
      idx[TT + b*L1 + m] = b*L1 + H0;
      if (m >= 1) out[b*LLEN + m - 1] = (float)H0;
    }
  }
  __syncthreads();
  if (tid == 0){
    float ssum = 0.f;
    for (int i2 = 0; i2 < 32; i2++) ssum += npart[i2];
    atomicAdd(out + 98368, ssum);
  }
}

// --------- K4: label bilinear as big-K MFMA GEMM, P generated on the fly ----------
// v6: split-K across wave halves. 512-thr block = 8 waves; waves 0-3 process
//     K-slices 0..259, waves 4-7 slices 260..519 for the SAME tokens (MSN
//     ms-groups/wave, 64*MSN tokens/block). Halves combined via LDS at the end.
//     Per B-fragment ds_read now feeds MSN MFMAs; 260 iterations (barriers
//     halved); staging dbuf'd per half with counted vmcnt(2) (v5 mechanics).
//     Grid exactly 256: blocks 0,1 -> MSN=5 (320 tok), blocks 2..255 -> MSN=4.
template<int MSN>
__device__ __forceinline__ void label_body(const float* E, const unsigned short* WtTp,
    const int* idx, const int* labbuf, const float* lblb, float* out,
    int t0, unsigned char* Bb, unsigned int* xls){
  int tid = threadIdx.x;
  int w = tid >> 6, lane = tid & 63, c = lane & 15, q = lane >> 4;
  int wgrp = w & 3, khalf = w >> 2;
  const int TOKB = MSN*64;

  const char* gW = (const char*)WtTp;
  // this thread's fixed B-chunk: chunk f holds WtTp[16*(f>>6)+(f&15)][s*32+((f>>4)&3)*8 ..+8)
  int f = tid;
  int bn = ((f >> 6) << 4) + (f & 15);
  int bkq = (f >> 4) & 3;
  const char* bsrc0 = gW + (size_t)bn*(KP*2) + (size_t)bkq*16;
  unsigned char* BbA = Bb;            // [3][8192] for K-half 0
  unsigned char* BbB = Bb + 3*8192;   // [3][8192] for K-half 1
  auto stage2 = [&](int s){
    __builtin_amdgcn_global_load_lds((gptr_t)(bsrc0 + (size_t)s*64),
        (sptr_t)(BbA + (s % 3)*8192 + f*16), 16, 0, 0);
    __builtin_amdgcn_global_load_lds((gptr_t)(bsrc0 + (size_t)(260 + s)*64),
        (sptr_t)(BbB + (s % 3)*8192 + f*16), 16, 0, 0);
  };
  stage2(0); stage2(1);

  // ---- stage gathered x rows (elh[g]) into LDS as bf16, stride-65-u32 ----
  for (int u = tid; u < TOKB*2; u += 512){
    int tok = u >> 1, half = u & 1;
    int tg = t0 + tok; int tc = tg < 2*TT ? tg : 0;
    int g = idx[tc];
    const float* xr = E + (size_t)g*NE + 512 + half*64;
    unsigned* dstx = &xls[tok*65 + half*32];
    #pragma unroll
    for (int j = 0; j < 16; j++){
      float4 v = *(const float4*)(xr + j*4);
      dstx[2*j]   = cvtpk(v.x, v.y);
      dstx[2*j+1] = cvtpk(v.z, v.w);
    }
  }

  const float *yvb[MSN], *xvb[MSN];
  int tokl[MSN];
  #pragma unroll
  for (int ms = 0; ms < MSN; ms++){
    int tl = (wgrp*MSN + ms)*16 + c;
    tokl[ms] = tl;
    int tu = t0 + tl; int tc = tu < 2*TT ? tu : 0;
    int tt = tc < TT ? tc : tc - TT;
    int g = idx[tc];
    yvb[ms] = E + (size_t)tt*NE + 640 + 8*q;   // elm row, this lane's q-offset
    xvb[ms] = E + (size_t)g*NE + 512 + 8*q;    // elh row (gathered)
  }
  f32x4 acc[MSN][8];
  #pragma unroll
  for (int ms = 0; ms < MSN; ms++)
    #pragma unroll
    for (int ns = 0; ns < 8; ns++){ acc[ms][ns][0]=0.f; acc[ms][ns][1]=0.f; acc[ms][ns][2]=0.f; acc[ms][ns][3]=0.f; }

  __syncthreads();   // xls visible (also drains prologue stages -- once, ok)

  const unsigned short* xsh = (const unsigned short*)xls;
  float xs[MSN];
  #pragma unroll
  for (int ms = 0; ms < MSN; ms++) xs[ms] = bf2f(xsh[tokl[ms]*130]);

  float yreg[MSN][8];
  unsigned ypk[MSN][4], xpk[MSN][4];
  int d = 0;
  for (int i = 0; i < 260; i++){
    // counted wait: pair(i) landed, pair(i+1) may stay in flight
    if (i == 259) { asm volatile("s_waitcnt vmcnt(0)" ::: "memory"); }
    else          { asm volatile("s_waitcnt vmcnt(2)" ::: "memory"); }
    __builtin_amdgcn_sched_barrier(0);
    __builtin_amdgcn_s_barrier();
    __builtin_amdgcn_sched_barrier(0);
    if (d == 0){
      int e0 = (khalf*2 + (i >= 130)) * 32;
      #pragma unroll
      for (int ms = 0; ms < MSN; ms++){
        float4 v0 = *(const float4*)(yvb[ms] + e0);
        float4 v1 = *(const float4*)(yvb[ms] + e0 + 4);
        yreg[ms][0]=v0.x; yreg[ms][1]=v0.y; yreg[ms][2]=v0.z; yreg[ms][3]=v0.w;
        yreg[ms][4]=v1.x; yreg[ms][5]=v1.y; yreg[ms][6]=v1.z; yreg[ms][7]=v1.w;
        ypk[ms][0]=cvtpk(v0.x,v0.y); ypk[ms][1]=cvtpk(v0.z,v0.w);
        ypk[ms][2]=cvtpk(v1.x,v1.y); ypk[ms][3]=cvtpk(v1.z,v1.w);
        float4 u0 = *(const float4*)(xvb[ms] + e0);
        float4 u1 = *(const float4*)(xvb[ms] + e0 + 4);
        xpk[ms][0]=cvtpk(u0.x,u0.y); xpk[ms][1]=cvtpk(u0.z,u0.w);
        xpk[ms][2]=cvtpk(u1.x,u1.y); xpk[ms][3]=cvtpk(u1.z,u1.w);
      }
    }
    bf16x8 afr[MSN];
    if (d < 128){
      #pragma unroll
      for (int ms = 0; ms < MSN; ms++){
        float xsc = xs[ms];
        union { unsigned u[4]; bf16x8 v; } uu;
        uu.u[0] = cvtpk(xsc*yreg[ms][0], xsc*yreg[ms][1]);
        uu.u[1] = cvtpk(xsc*yreg[ms][2], xsc*yreg[ms][3]);
        uu.u[2] = cvtpk(xsc*yreg[ms][4], xsc*yreg[ms][5]);
        uu.u[3] = cvtpk(xsc*yreg[ms][6], xsc*yreg[ms][7]);
        afr[ms] = uu.v;
      }
      // prefetch next-consumed x element (d+1, or x[0] for the next phase)
      int dnn = (d == 127) ? 0 : d + 1;
      #pragma unroll
      for (int ms = 0; ms < MSN; ms++) xs[ms] = bf2f(xsh[tokl[ms]*130 + dnn]);
    } else if (d == 128){
      #pragma unroll
      for (int ms = 0; ms < MSN; ms++){
        union { unsigned u[4]; bf16x8 v; } uu;
        uu.u[0]=xpk[ms][0]; uu.u[1]=xpk[ms][1]; uu.u[2]=xpk[ms][2]; uu.u[3]=xpk[ms][3];
        afr[ms] = uu.v;
      }
    } else {
      #pragma unroll
      for (int ms = 0; ms < MSN; ms++){
        union { unsigned u[4]; bf16x8 v; } uu;
        uu.u[0]=ypk[ms][0]; uu.u[1]=ypk[ms][1]; uu.u[2]=ypk[ms][2]; uu.u[3]=ypk[ms][3];
        afr[ms] = uu.v;
      }
    }
    if (i + 2 < 260) stage2(i + 2);
    const char* bs = (const char*)((khalf ? BbB : BbA) + (i % 3)*8192);
    #pragma unroll
    for (int ns = 0; ns < 8; ns++){
      bf16x8 bfr = *(const bf16x8*)(bs + ns*1024 + lane*16);
      #pragma unroll
      for (int ms = 0; ms < MSN; ms++)
        acc[ms][ns] = __builtin_amdgcn_mfma_f32_16x16x32_bf16(afr[ms], bfr, acc[ms][ns], 0, 0, 0);
    }
    d++; if (d == 130) d = 0;
  }

  // ---- combine K-halves through LDS (reuses xls region), MSN rounds of 32KB ----
  __syncthreads();
  float* cmb = (float*)xls;
  #pragma unroll
  for (int ms = 0; ms < MSN; ms++){
    if (khalf == 1){
      #pragma unroll
      for (int ns = 0; ns < 8; ns++)
        *(f32x4*)&cmb[((wgrp*64 + lane)*8 + ns)*4] = acc[ms][ns];
    }
    __syncthreads();
    if (khalf == 0){
      #pragma unroll
      for (int ns = 0; ns < 8; ns++){
        f32x4 t = *(const f32x4*)&cmb[((wgrp*64 + lane)*8 + ns)*4];
        acc[ms][ns][0] += t[0]; acc[ms][ns][1] += t[1];
        acc[ms][ns][2] += t[2]; acc[ms][ns][3] += t[3];
      }
    }
    __syncthreads();
  }
  if (khalf == 1) return;   // no barriers past this point

  // ---- epilogue (khalf0 waves): C row = token (4q+i), col n = 16*ns + c ----
  float bv[8];
  #pragma unroll
  for (int ns = 0; ns < 8; ns++) bv[ns] = lblb[ns*16 + c];
  float part = 0.f;
  #pragma unroll
  for (int ms = 0; ms < MSN; ms++){
    int tb = t0 + (wgrp*MSN + ms)*16 + 4*q;
    float mx[4] = {-3.4e38f, -3.4e38f, -3.4e38f, -3.4e38f};
    #pragma unroll
    for (int ns = 0; ns < 8; ns++)
      #pragma unroll
      for (int i = 0; i < 4; i++){
        float v = acc[ms][ns][i] + bv[ns];
        mx[i] = fmaxf(mx[i], v);
      }
    #pragma unroll
    for (int o = 1; o < 16; o <<= 1)
      #pragma unroll
      for (int i = 0; i < 4; i++) mx[i] = fmaxf(mx[i], __shfl_xor(mx[i], o, 64));
    int lab[4];
    #pragma unroll
    for (int i = 0; i < 4; i++){
      int tu = tb + i; int tc2 = tu < 2*TT ? tu : 0;
      int tt = tc2 < TT ? tc2 : tc2 - TT;
      lab[i] = (tu < TT) ? labbuf[tt] : 0;
    }
    float se[4] = {0.f,0.f,0.f,0.f}, gp[4] = {0.f,0.f,0.f,0.f};
    #pragma unroll
    for (int ns = 0; ns < 8; ns++)
      #pragma unroll
      for (int i = 0; i < 4; i++){
        float v = acc[ms][ns][i] + bv[ns];
        se[i] += expf(v - mx[i]);
        if (ns*16 + c == lab[i]) gp[i] += v;
      }
    #pragma unroll
    for (int o = 1; o < 16; o <<= 1)
      #pragma unroll
      for (int i = 0; i < 4; i++){ se[i] += __shfl_xor(se[i], o, 64); gp[i] += __shfl_xor(gp[i], o, 64); }
    if (c == 0){
      #pragma unroll
      for (int i = 0; i < 4; i++){
        int tu = tb + i;
        if (tu < 2*TT){
          int tt = tu < TT ? tu : tu - TT;
          int mm = tt % L1;
          if (tu < TT){
            if (mm) part += mx[i] + logf(se[i]) - gp[i];
          } else {
            if (mm) out[32768 + (tt / L1)*LLEN + mm - 1] = mx[i];
          }
        }
      }
    }
  }
  for (int o = 1; o < 64; o <<= 1) part += __shfl_xor(part, o, 64);
  if (lane == 0 && part != 0.f) atomicAdd(out + 98369, part);
}

__global__ __launch_bounds__(512, 2) void k_label(const float* E, const unsigned short* WtTp,
    const int* idx, const int* labbuf, const float* lblb, float* out){
  __shared__ __align__(16) unsigned char Bst[6*8192];      // 2 K-halves x 3 bufs
  __shared__ __align__(16) unsigned int xls[20800];        // up to 320 tok x 65 u32
  int bx = blockIdx.x;
  if (bx < 2)
    label_body<5>(E, WtTp, idx, labbuf, lblb, out, bx*320, Bst, xls);
  else
    label_body<4>(E, WtTp, idx, labbuf, lblb, out, 640 + (bx - 2)*256, Bst, xls);
}

extern "C" void kernel_launch(void* const* d_in, const int* in_sizes, int n_in,
                              void* d_out, int out_size, void* d_ws, size_t ws_size,
                              hipStream_t stream){
  const float* memory_bank = (const float*)d_in[0];
  const int* edge_heads = (const int*)d_in[1];
  const int* edge_labels = (const int*)d_in[2];
  const int* mask = (const int*)d_in[4];
  const float* sentinel = (const float*)d_in[5];
  const float* W_enh = (const float*)d_in[6];  const float* b_enh = (const float*)d_in[7];
  const float* W_enm = (const float*)d_in[8];  const float* b_enm = (const float*)d_in[9];
  const float* W_elh = (const float*)d_in[10]; const float* b_elh = (const float*)d_in[11];
  const float* W_elm = (const float*)d_in[12]; const float* b_elm = (const float*)d_in[13];
  const float* ba_U = (const float*)d_in[14];  const float* ba_Wd = (const float*)d_in[15];
  const float* ba_We = (const float*)d_in[16]; const float* ba_b = (const float*)d_in[17];
  const float* lbl_U = (const float*)d_in[18]; const float* lbl_Wl = (const float*)d_in[19];
  const float* lbl_Wr = (const float*)d_in[20]; const float* lbl_b = (const float*)d_in[21];
  float* out = (float*)d_out;

  char* wsc = (char*)d_ws;
  size_t o = 0;
  auto alloc = [&](size_t n){ o = (o + 255) & ~(size_t)255; void* pp = wsc + o; o += n; return pp; };
  float* E     = (float*)alloc((size_t)TT*NE*4);
  float* T1    = (float*)alloc((size_t)TT*256*4);
  float* S     = (float*)alloc((size_t)BB*L1*L1*4);
  float* Wcat  = (float*)alloc((size_t)HH*NE*4);
  float* bcat  = (float*)alloc((size_t)NE*4);
  unsigned short* WtTp = (unsigned short*)alloc((size_t)128*KP*2);
  float* dvec  = (float*)alloc((size_t)TT*4);
  float* evec  = (float*)alloc((size_t)TT*4);
  int*   idx   = (int*)alloc((size_t)2*TT*4);
  int*   labbuf= (int*)alloc((size_t)TT*4);

  k_init<<<dim3(129), 256, 0, stream>>>(edge_heads, edge_labels, out, idx, labbuf);
  k_wcat<<<dim3(1200), 256, 0, stream>>>(W_enh, b_enh, W_enm, b_enm, W_elh, b_elh, W_elm, b_elm, Wcat, bcat);
  k_wtt<<<dim3(65, 128), 256, 0, stream>>>(lbl_U, lbl_Wl, lbl_Wr, WtTp);
  k_enc<<<dim3(257, 6), 256, 0, stream>>>(memory_bank, sentinel, Wcat, bcat, E);
  k_t1<<<dim3(257, 2), 256, 0, stream>>>(E, ba_U, T1);
  k_vecs<<<dim3(8208), 256, 0, stream>>>(E, ba_Wd, ba_We, ba_b, dvec, evec);
  k_ns<<<dim3(25, 64), 256, 0, stream>>>(T1, E, dvec, evec, S);
  k_nodecol<<<dim3(17, 64), 256, 0, stream>>>(S, edge_heads, mask, out, idx);
  k_label<<<dim3(256), 512, 0, stream>>>(E, WtTp, idx, labbuf, lbl_b, out);
}

// Round 5
// 1072.336 us; speedup vs baseline: 1.4391x; 1.4391x over previous
//
#include <hip/hip_runtime.h>
#include <hip/hip_bf16.h>

#define BB 64
#define LLEN 512
#define HH 400
#define L1 513
#define TT 32832      // BB*L1
#define NE 768        // enh(256)|enm(256)|elh(128)|elm(128)
#define KP 16640      // 16384 bilinear + 128 Wl + 128 Wr (phase-permuted)
#define PHW 4160      // per-phase k' width: 130 d-slices * 32

typedef __attribute__((ext_vector_type(4))) float f32x4;
typedef __attribute__((ext_vector_type(8))) short bf16x8;
typedef unsigned int u32;
typedef __attribute__((address_space(1))) const u32* gptr_t;
typedef __attribute__((address_space(3))) u32* sptr_t;

// round-to-nearest-even f32 -> bf16 (finite inputs)
__device__ inline unsigned short f2bf(float x){
  unsigned u = __float_as_uint(x);
  unsigned r = (u + 0x7fffu + ((u >> 16) & 1u)) >> 16;
  return (unsigned short)r;
}
// packed RNE f32x2 -> bf16x2 in one instruction (lo = a, hi = b)
__device__ inline unsigned cvtpk(float a, float b){
  unsigned r;
  asm("v_cvt_pk_bf16_f32 %0, %1, %2" : "=v"(r) : "v"(a), "v"(b));
  return r;
}
__device__ inline float bf2f(unsigned short h){
  return __uint_as_float(((unsigned)h) << 16);
}

// ---------------- init: labels1 output, gold gather idx, label buf, zero nll ----
__global__ __launch_bounds__(256) void k_init(const int* eh, const int* el, float* out,
                                              int* idx, int* labbuf){
  int t = blockIdx.x*256 + threadIdx.x;
  if (t < TT){
    int b = t / L1, m = t - b*L1;
    int lab = m ? el[b*LLEN + m - 1] : 0;
    int hd  = m ? eh[b*LLEN + m - 1] : 0;
    out[65536 + t] = (float)lab;
    labbuf[t] = lab;
    idx[t] = b*L1 + hd;
  }
  if (blockIdx.x == 0 && threadIdx.x < 2) out[98368 + threadIdx.x] = 0.f;
}

// ---------------- build concatenated encoder weights ----------------
__global__ __launch_bounds__(256) void k_wcat(const float* Wenh,const float* benh,
    const float* Wenm,const float* benm,const float* Welh,const float* belh,
    const float* Welm,const float* belm,float* Wcat,float* bcat){
  int g = blockIdx.x*256 + threadIdx.x;
  if (g < HH*NE){
    int k = g / NE, n = g - k*NE;
    float v;
    if (n < 256) v = Wenh[k*256 + n];
    else if (n < 512) v = Wenm[k*256 + n - 256];
    else if (n < 640) v = Welh[k*128 + n - 512];
    else v = Welm[k*128 + n - 640];
    Wcat[g] = v;
  }
  if (g < NE){
    float v;
    if (g < 256) v = benh[g];
    else if (g < 512) v = benm[g - 256];
    else if (g < 640) v = belh[g - 512];
    else v = belm[g - 640];
    bcat[g] = v;
  }
}

// ------------- build WtTp[n][k'] bf16, K phase-permuted: k' = p*4160 + d*32 + j,
// (p,d,j): d<128 -> U[n][d][32p+j]; d==128 -> Wl[n][32p+j]; d==129 -> Wr[n][32p+j]
__global__ __launch_bounds__(256) void k_wtt(const float* lblU, const float* Wl,
    const float* Wr, unsigned short* WtTp){
  int n = blockIdx.y;
  int kp = blockIdx.x*256 + threadIdx.x;
  if (kp >= KP) return;
  int p = kp / PHW; int q2 = kp - p*PHW; int dd = q2 >> 5; int j = q2 & 31; int e = p*32 + j;
  float v;
  if (dd < 128) v = lblU[(size_t)n*16384 + dd*128 + e];
  else if (dd == 128) v = Wl[n*128 + e];
  else v = Wr[n*128 + e];
  WtTp[(size_t)n*KP + kp] = f2bf(v);
}

#define INNER8(AS, BS) \
  _Pragma("unroll") \
  for (int kk = 0; kk < 8; kk++){ \
    float4 a0 = *(const float4*)&AS[kk][ty*8]; \
    float4 a1 = *(const float4*)&AS[kk][ty*8+4]; \
    float4 b0 = *(const float4*)&BS[kk][tx*8]; \
    float4 b1 = *(const float4*)&BS[kk][tx*8+4]; \
    float avv[8] = {a0.x,a0.y,a0.z,a0.w,a1.x,a1.y,a1.z,a1.w}; \
    float bvv[8] = {b0.x,b0.y,b0.z,b0.w,b1.x,b1.y,b1.z,b1.w}; \
    _Pragma("unroll") \
    for (int ii = 0; ii < 8; ii++) \
      _Pragma("unroll") \
      for (int jj = 0; jj < 8; jj++) \
        c_[ii][jj] += avv[ii]*bvv[jj]; \
  }

// ---------------- K1: E = elu([sentinel;mb] @ Wcat + bcat), fp32 128x128x8 tile ----
__global__ __launch_bounds__(256) void k_enc(const float* mb, const float* sent,
    const float* Wcat, const float* bcat, float* E){
  __shared__ float As[8][132];
  __shared__ float Bs[8][132];
  int tid = threadIdx.x, tx = tid & 15, ty = tid >> 4;
  int Mb = blockIdx.x * 128, n0 = blockIdx.y * 128;
  int ar = tid >> 1, akc = (tid & 1) * 4;
  int row = Mb + ar;
  bool aval = row < TT;
  const float* ap = sent;
  if (aval){
    int br = row / L1, mr = row - br*L1;
    if (mr) ap = mb + (size_t)(br*LLEN + mr - 1)*HH;
  }
  int bkr = tid >> 5, bnc = (tid & 31) * 4;
  float c_[8][8] = {};
  for (int k0 = 0; k0 < HH; k0 += 8){
    __syncthreads();
    float4 av = make_float4(0.f,0.f,0.f,0.f);
    if (aval) av = *(const float4*)(ap + k0 + akc);
    As[akc+0][ar] = av.x; As[akc+1][ar] = av.y; As[akc+2][ar] = av.z; As[akc+3][ar] = av.w;
    *(float4*)&Bs[bkr][bnc] = *(const float4*)(Wcat + (size_t)(k0 + bkr)*NE + n0 + bnc);
    __syncthreads();
    INNER8(As, Bs)
  }
  #pragma unroll
  for (int i = 0; i < 8; i++){
    int rr = Mb + ty*8 + i;
    if (rr < TT){
      float4 o0, o1;
      float t0v;
      t0v = c_[i][0] + bcat[n0+tx*8+0]; o0.x = t0v > 0.f ? t0v : expm1f(t0v);
      t0v = c_[i][1] + bcat[n0+tx*8+1]; o0.y = t0v > 0.f ? t0v : expm1f(t0v);
      t0v = c_[i][2] + bcat[n0+tx*8+2]; o0.z = t0v > 0.f ? t0v : expm1f(t0v);
      t0v = c_[i][3] + bcat[n0+tx*8+3]; o0.w = t0v > 0.f ? t0v : expm1f(t0v);
      t0v = c_[i][4] + bcat[n0+tx*8+4]; o1.x = t0v > 0.f ? t0v : expm1f(t0v);
      t0v = c_[i][5] + bcat[n0+tx*8+5]; o1.y = t0v > 0.f ? t0v : expm1f(t0v);
      t0v = c_[i][6] + bcat[n0+tx*8+6]; o1.z = t0v > 0.f ? t0v : expm1f(t0v);
      t0v = c_[i][7] + bcat[n0+tx*8+7]; o1.w = t0v > 0.f ? t0v : expm1f(t0v);
      *(float4*)&E[(size_t)rr*NE + n0 + tx*8] = o0;
      *(float4*)&E[(size_t)rr*NE + n0 + tx*8 + 4] = o1;
    }
  }
}

// ---------------- K2: T1 = enh @ ba_U ----------------
__global__ __launch_bounds__(256) void k_t1(const float* E, const float* baU, float* T1){
  __shared__ float As[8][132];
  __shared__ float Bs[8][132];
  int tid = threadIdx.x, tx = tid & 15, ty = tid >> 4;
  int Mb = blockIdx.x * 128, n0 = blockIdx.y * 128;
  int ar = tid >> 1, akc = (tid & 1) * 4;
  int row = Mb + ar;
  bool aval = row < TT;
  const float* ap = E + (size_t)(aval ? row : 0)*NE;
  int bkr = tid >> 5, bnc = (tid & 31) * 4;
  float c_[8][8] = {};
  for (int k0 = 0; k0 < 256; k0 += 8){
    __syncthreads();
    float4 av = make_float4(0.f,0.f,0.f,0.f);
    if (aval) av = *(const float4*)(ap + k0 + akc);
    As[akc+0][ar] = av.x; As[akc+1][ar] = av.y; As[akc+2][ar] = av.z; As[akc+3][ar] = av.w;
    *(float4*)&Bs[bkr][bnc] = *(const float4*)(baU + (size_t)(k0 + bkr)*256 + n0 + bnc);
    __syncthreads();
    INNER8(As, Bs)
  }
  #pragma unroll
  for (int i = 0; i < 8; i++){
    int rr = Mb + ty*8 + i;
    if (rr < TT){
      float4 o0 = {c_[i][0],c_[i][1],c_[i][2],c_[i][3]};
      float4 o1 = {c_[i][4],c_[i][5],c_[i][6],c_[i][7]};
      *(float4*)&T1[(size_t)rr*256 + n0 + tx*8] = o0;
      *(float4*)&T1[(size_t)rr*256 + n0 + tx*8 + 4] = o1;
    }
  }
}

// ---------------- K2b: dvec = enh@ba_Wd + ba_b ; evec = enm@ba_We ----------------
__global__ __launch_bounds__(256) void k_vecs(const float* E, const float* Wd,
    const float* We, const float* bab, float* dvec, float* evec){
  int w = threadIdx.x >> 6, lane = threadIdx.x & 63;
  int t = blockIdx.x*4 + w;
  const float* enh = E + (size_t)t*NE;
  const float* enm = enh + 256;
  float sd = 0.f, se = 0.f;
  for (int l = lane; l < 256; l += 64){ sd += enh[l]*Wd[l]; se += enm[l]*We[l]; }
  for (int o = 1; o < 64; o <<= 1){ sd += __shfl_xor(sd, o, 64); se += __shfl_xor(se, o, 64); }
  if (lane == 0){ dvec[t] = sd + bab[0]; evec[t] = se; }
}

// ---------------- K3a: S[b,h,m] = T1[b,h,:]·enm[b,m,:] + dvec[h] + evec[m] ----------
__global__ __launch_bounds__(256) void k_ns(const float* T1, const float* E,
    const float* dvec, const float* evec, float* S){
  __shared__ float As[8][132];
  __shared__ float Bs[8][132];
  int tid = threadIdx.x, tx = tid & 15, ty = tid >> 4;
  int b = blockIdx.y;
  int tm = blockIdx.x / 5, tn = blockIdx.x - tm*5;
  int Mb = tm*128, n0 = tn*128;
  int ar = tid >> 1, akc = (tid & 1) * 4;
  int hrow = Mb + ar; bool aval = hrow < L1;
  const float* ap = T1 + ((size_t)b*L1 + (aval ? hrow : 0))*256;
  int mrow = n0 + ar; bool bval = mrow < L1;
  const float* bp = E + ((size_t)b*L1 + (bval ? mrow : 0))*NE + 256;
  float c_[8][8] = {};
  for (int k0 = 0; k0 < 256; k0 += 8){
    __syncthreads();
    float4 av = make_float4(0.f,0.f,0.f,0.f);
    float4 bv2 = make_float4(0.f,0.f,0.f,0.f);
    if (aval) av = *(const float4*)(ap + k0 + akc);
    if (bval) bv2 = *(const float4*)(bp + k0 + akc);
    As[akc+0][ar] = av.x; As[akc+1][ar] = av.y; As[akc+2][ar] = av.z; As[akc+3][ar] = av.w;
    Bs[akc+0][ar] = bv2.x; Bs[akc+1][ar] = bv2.y; Bs[akc+2][ar] = bv2.z; Bs[akc+3][ar] = bv2.w;
    __syncthreads();
    INNER8(As, Bs)
  }
  float dr[8], er[8];
  #pragma unroll
  for (int i = 0; i < 8; i++){ int h = Mb + ty*8 + i; dr[i] = (h < L1) ? dvec[b*L1 + h] : 0.f; }
  #pragma unroll
  for (int j = 0; j < 8; j++){ int m = n0 + tx*8 + j; er[j] = (m < L1) ? evec[b*L1 + m] : 0.f; }
  float* Sb = S + (size_t)b*L1*L1;
  #pragma unroll
  for (int i = 0; i < 8; i++){
    int h = Mb + ty*8 + i;
    if (h < L1){
      #pragma unroll
      for (int j = 0; j < 8; j++){
        int m = n0 + tx*8 + j;
        if (m < L1) Sb[(size_t)h*L1 + m] = c_[i][j] + dr[i] + er[j];
      }
    }
  }
}

// --------- K3b: per-column log-softmax(gold) + node_nll + argmax decode -----------
__global__ __launch_bounds__(256) void k_nodecol(const float* S, const int* eh,
    const int* mask, float* out, int* idx){
  int b = blockIdx.y, mt = blockIdx.x;
  __shared__ float msk[L1];
  __shared__ float rM[8][32], rS[8][32], rG[8][32], rB[8][32];
  __shared__ int rH[8][32];
  __shared__ float npart[32];
  int tid = threadIdx.x; int c = tid & 31, r = tid >> 5;
  for (int h = tid; h < L1; h += 256) msk[h] = h ? (float)mask[b*LLEN + h - 1] : 0.f;
  __syncthreads();
  int m = mt*32 + c; bool valid = m < L1; int mc = valid ? m : (L1-1);
  float maskm = msk[mc];
  int gold = 0; if (valid && m) gold = eh[b*LLEN + m - 1];
  const float* Sb = S + (size_t)b*L1*L1;
  float Mx = -3.4e38f, Sm = 0.f, G = 0.f, Bv = -3.4e38f; int Bh = 0;
  for (int h = r; h < L1; h += 8){
    float s = Sb[(size_t)h*L1 + mc];
    float adj = s + ((msk[h] + maskm) > 1.5f ? 0.69314718055994531f : 0.f);
    float nm = fmaxf(Mx, adj);
    Sm = Sm * expf(Mx - nm) + expf(adj - nm);
    Mx = nm;
    if (h == gold) G = adj;
    float dv = (h == m) ? -3.4e38f : (s + (msk[h] > 0.5f ? 0.f : -1e8f));
    if (dv > Bv){ Bv = dv; Bh = h; }
  }
  rM[r][c] = Mx; rS[r][c] = Sm; rG[r][c] = G; rB[r][c] = Bv; rH[r][c] = Bh;
  __syncthreads();
  if (r == 0){
    float M0 = rM[0][c], S0 = rS[0][c], G0 = rG[0][c], B0 = rB[0][c]; int H0 = rH[0][c];
    for (int rr = 1; rr < 8; rr++){
      float m2 = rM[rr][c], s2 = rS[rr][c];
      float nm = fmaxf(M0, m2);
      S0 = S0*expf(M0 - nm) + s2*expf(m2 - nm); M0 = nm;
      G0 += rG[rr][c];
      float b2 = rB[rr][c]; int h2 = rH[rr][c];
      if (b2 > B0 || (b2 == B0 && h2 < H0)){ B0 = b2; H0 = h2; }
    }
    float nll = 0.f;
    if (valid && m >= 1) nll = (M0 + logf(S0)) - G0;
    npart[c] = nll;
    if (valid){
      idx[TT + b*L1 + m] = b*L1 + H0;
      if (m >= 1) out[b*LLEN + m - 1] = (float)H0;
    }
  }
  __syncthreads();
  if (tid == 0){
    float ssum = 0.f;
    for (int i2 = 0; i2 < 32; i2++) ssum += npart[i2];
    atomicAdd(out + 98368, ssum);
  }
}

// --------- K4: label bilinear as big-K MFMA GEMM, P generated on the fly ----------
// v7: v6 split-K fixed. Compact token space: of 65664 (gold+pred) tokens,
//     exactly 128 are m==0 padding -> useful = 65536 = 256 x 256 exactly.
//     Blocks 0..127 gold, 128..255 pred (block-uniform), 256 tokens/block,
//     MSN=4 uniform, no remainder. __launch_bounds__(512,1) -> 256-VGPR cap
//     (v6 spilled at 128); ypk/xpk dropped (d==128 refetch global, d==129
//     rebuild from yreg). Combine slots swizzled by (ns+lane)&7 (8-way max).
__global__ __launch_bounds__(512, 1) void k_label(const float* E, const unsigned short* WtTp,
    const int* idx, const int* labbuf, const float* lblb, float* out){
  __shared__ __align__(16) unsigned char Bst[6*8192];   // 2 K-halves x 3 bufs
  __shared__ __align__(16) unsigned int xls[256*65];    // 256 tok x 130 bf16, stride 65 u32
  int tid = threadIdx.x;
  int w = tid >> 6, lane = tid & 63, c = lane & 15, q = lane >> 4;
  int wgrp = w & 3, khalf = w >> 2;
  int bx = blockIdx.x;
  bool pred = bx >= 128;
  int q0 = (bx & 127) * 256;        // compact index within pass: q -> (b=q>>9, m=(q&511)+1)
  int ibase = pred ? TT : 0;

  const char* gW = (const char*)WtTp;
  // this thread's fixed B-chunk: chunk f holds WtTp[16*(f>>6)+(f&15)][s*32+((f>>4)&3)*8 ..+8)
  int f = tid;
  int bn = ((f >> 6) << 4) + (f & 15);
  int bkq = (f >> 4) & 3;
  const char* bsrc0 = gW + (size_t)bn*(KP*2) + (size_t)bkq*16;
  unsigned char* BbA = Bst;            // [3][8192] for K-half 0
  unsigned char* BbB = Bst + 3*8192;   // [3][8192] for K-half 1
  auto stage2 = [&](int s){
    __builtin_amdgcn_global_load_lds((gptr_t)(bsrc0 + (size_t)s*64),
        (sptr_t)(BbA + (s % 3)*8192 + f*16), 16, 0, 0);
    __builtin_amdgcn_global_load_lds((gptr_t)(bsrc0 + (size_t)(260 + s)*64),
        (sptr_t)(BbB + (s % 3)*8192 + f*16), 16, 0, 0);
  };
  stage2(0); stage2(1);

  // ---- stage gathered x rows (elh[g]) into LDS as bf16 (1 half-row/thread) ----
  {
    int tok = tid >> 1, half = tid & 1;
    int qq = q0 + tok;
    int trow = (qq >> 9)*L1 + (qq & 511) + 1;
    int g = idx[ibase + trow];
    const float* xr = E + (size_t)g*NE + 512 + half*64;
    unsigned* dstx = &xls[tok*65 + half*32];
    #pragma unroll
    for (int j = 0; j < 16; j++){
      float4 v = *(const float4*)(xr + j*4);
      dstx[2*j]   = cvtpk(v.x, v.y);
      dstx[2*j+1] = cvtpk(v.z, v.w);
    }
  }

  const float *yvb[4], *xvb[4];
  int tokl[4];
  #pragma unroll
  for (int ms = 0; ms < 4; ms++){
    int tl = (wgrp*4 + ms)*16 + c;
    tokl[ms] = tl;
    int qq = q0 + tl;
    int trow = (qq >> 9)*L1 + (qq & 511) + 1;
    int g = idx[ibase + trow];
    yvb[ms] = E + (size_t)trow*NE + 640 + 8*q;   // elm row, this lane's q-offset
    xvb[ms] = E + (size_t)g*NE + 512 + 8*q;      // elh row (gathered)
  }
  f32x4 acc[4][8];
  #pragma unroll
  for (int ms = 0; ms < 4; ms++)
    #pragma unroll
    for (int ns = 0; ns < 8; ns++){ acc[ms][ns][0]=0.f; acc[ms][ns][1]=0.f; acc[ms][ns][2]=0.f; acc[ms][ns][3]=0.f; }

  __syncthreads();   // xls visible (also drains prologue stages -- once, ok)

  const unsigned short* xsh = (const unsigned short*)xls;
  float xs[4];
  #pragma unroll
  for (int ms = 0; ms < 4; ms++) xs[ms] = bf2f(xsh[tokl[ms]*130]);

  float yreg[4][8];
  int d = 0;
  for (int i = 0; i < 260; i++){
    // counted wait: pair(i) landed, pair(i+1) may stay in flight
    if (i == 259) { asm volatile("s_waitcnt vmcnt(0)" ::: "memory"); }
    else          { asm volatile("s_waitcnt vmcnt(2)" ::: "memory"); }
    __builtin_amdgcn_sched_barrier(0);
    __builtin_amdgcn_s_barrier();
    __builtin_amdgcn_sched_barrier(0);
    if (d == 0){
      int e0 = (khalf*2 + (i >= 130)) * 32;
      #pragma unroll
      for (int ms = 0; ms < 4; ms++){
        float4 v0 = *(const float4*)(yvb[ms] + e0);
        float4 v1 = *(const float4*)(yvb[ms] + e0 + 4);
        yreg[ms][0]=v0.x; yreg[ms][1]=v0.y; yreg[ms][2]=v0.z; yreg[ms][3]=v0.w;
        yreg[ms][4]=v1.x; yreg[ms][5]=v1.y; yreg[ms][6]=v1.z; yreg[ms][7]=v1.w;
      }
    }
    bf16x8 afr[4];
    if (d < 128){
      #pragma unroll
      for (int ms = 0; ms < 4; ms++){
        float xsc = xs[ms];
        union { unsigned u[4]; bf16x8 v; } uu;
        uu.u[0] = cvtpk(xsc*yreg[ms][0], xsc*yreg[ms][1]);
        uu.u[1] = cvtpk(xsc*yreg[ms][2], xsc*yreg[ms][3]);
        uu.u[2] = cvtpk(xsc*yreg[ms][4], xsc*yreg[ms][5]);
        uu.u[3] = cvtpk(xsc*yreg[ms][6], xsc*yreg[ms][7]);
        afr[ms] = uu.v;
      }
      // prefetch next-consumed x element (d+1, or x[0] for the next phase)
      int dnn = (d == 127) ? 0 : d + 1;
      #pragma unroll
      for (int ms = 0; ms < 4; ms++) xs[ms] = bf2f(xsh[tokl[ms]*130 + dnn]);
    } else if (d == 128){
      // rare (2/260 iters): A-frag = bf16(x[e0+8q ..]) loaded fresh from global
      int e0 = (khalf*2 + (i >= 130)) * 32;
      #pragma unroll
      for (int ms = 0; ms < 4; ms++){
        float4 u0 = *(const float4*)(xvb[ms] + e0);
        float4 u1 = *(const float4*)(xvb[ms] + e0 + 4);
        union { unsigned u[4]; bf16x8 v; } uu;
        uu.u[0]=cvtpk(u0.x,u0.y); uu.u[1]=cvtpk(u0.z,u0.w);
        uu.u[2]=cvtpk(u1.x,u1.y); uu.u[3]=cvtpk(u1.z,u1.w);
        afr[ms] = uu.v;
      }
    } else {
      // d == 129, rare: A-frag = bf16(y[e0+8q ..]) rebuilt from yreg
      #pragma unroll
      for (int ms = 0; ms < 4; ms++){
        union { unsigned u[4]; bf16x8 v; } uu;
        uu.u[0]=cvtpk(yreg[ms][0],yreg[ms][1]); uu.u[1]=cvtpk(yreg[ms][2],yreg[ms][3]);
        uu.u[2]=cvtpk(yreg[ms][4],yreg[ms][5]); uu.u[3]=cvtpk(yreg[ms][6],yreg[ms][7]);
        afr[ms] = uu.v;
      }
    }
    if (i + 2 < 260) stage2(i + 2);
    const char* bs = (const char*)((khalf ? BbB : BbA) + (i % 3)*8192);
    #pragma unroll
    for (int ns = 0; ns < 8; ns++){
      bf16x8 bfr = *(const bf16x8*)(bs + ns*1024 + lane*16);
      #pragma unroll
      for (int ms = 0; ms < 4; ms++)
        acc[ms][ns] = __builtin_amdgcn_mfma_f32_16x16x32_bf16(afr[ms], bfr, acc[ms][ns], 0, 0, 0);
    }
    d++; if (d == 130) d = 0;
  }

  // ---- combine K-halves through LDS (reuses xls region), 4 rounds of 32KB ----
  // slot swizzled by (ns+lane)&7: banks spread 8-way instead of 32-way.
  __syncthreads();
  float* cmb = (float*)xls;
  #pragma unroll
  for (int ms = 0; ms < 4; ms++){
    if (khalf == 1){
      #pragma unroll
      for (int ns = 0; ns < 8; ns++)
        *(f32x4*)&cmb[((wgrp*64 + lane)*8 + ((ns + lane) & 7))*4] = acc[ms][ns];
    }
    __syncthreads();
    if (khalf == 0){
      #pragma unroll
      for (int ns = 0; ns < 8; ns++){
        f32x4 t = *(const f32x4*)&cmb[((wgrp*64 + lane)*8 + ((ns + lane) & 7))*4];
        acc[ms][ns][0] += t[0]; acc[ms][ns][1] += t[1];
        acc[ms][ns][2] += t[2]; acc[ms][ns][3] += t[3];
      }
    }
    __syncthreads();
  }
  if (khalf == 1) return;   // no barriers past this point

  // ---- epilogue (khalf0 waves): C row = token (4q+i), col n = 16*ns + c ----
  float bv[8];
  #pragma unroll
  for (int ns = 0; ns < 8; ns++) bv[ns] = lblb[ns*16 + c];
  float part = 0.f;
  #pragma unroll
  for (int ms = 0; ms < 4; ms++){
    int tb = (wgrp*4 + ms)*16 + 4*q;       // local token base
    float mx[4] = {-3.4e38f, -3.4e38f, -3.4e38f, -3.4e38f};
    #pragma unroll
    for (int ns = 0; ns < 8; ns++)
      #pragma unroll
      for (int i = 0; i < 4; i++){
        float v = acc[ms][ns][i] + bv[ns];
        mx[i] = fmaxf(mx[i], v);
      }
    #pragma unroll
    for (int o = 1; o < 16; o <<= 1)
      #pragma unroll
      for (int i = 0; i < 4; i++) mx[i] = fmaxf(mx[i], __shfl_xor(mx[i], o, 64));
    if (!pred){
      int lab[4];
      #pragma unroll
      for (int i = 0; i < 4; i++){
        int qq = q0 + tb + i;
        int trow = (qq >> 9)*L1 + (qq & 511) + 1;
        lab[i] = labbuf[trow];
      }
      float se[4] = {0.f,0.f,0.f,0.f}, gp[4] = {0.f,0.f,0.f,0.f};
      #pragma unroll
      for (int ns = 0; ns < 8; ns++)
        #pragma unroll
        for (int i = 0; i < 4; i++){
          float v = acc[ms][ns][i] + bv[ns];
          se[i] += expf(v - mx[i]);
          if (ns*16 + c == lab[i]) gp[i] += v;
        }
      #pragma unroll
      for (int o = 1; o < 16; o <<= 1)
        #pragma unroll
        for (int i = 0; i < 4; i++){ se[i] += __shfl_xor(se[i], o, 64); gp[i] += __shfl_xor(gp[i], o, 64); }
      if (c == 0){
        #pragma unroll
        for (int i = 0; i < 4; i++) part += mx[i] + logf(se[i]) - gp[i];
      }
    } else {
      if (c == 0){
        #pragma unroll
        for (int i = 0; i < 4; i++)
          out[32768 + q0 + tb + i] = mx[i];   // pred slot = 32768 + compact q
      }
    }
  }
  if (!pred){
    for (int o = 1; o < 64; o <<= 1) part += __shfl_xor(part, o, 64);
    if (lane == 0) atomicAdd(out + 98369, part);
  }
}

extern "C" void kernel_launch(void* const* d_in, const int* in_sizes, int n_in,
                              void* d_out, int out_size, void* d_ws, size_t ws_size,
                              hipStream_t stream){
  const float* memory_bank = (const float*)d_in[0];
  const int* edge_heads = (const int*)d_in[1];
  const int* edge_labels = (const int*)d_in[2];
  const int* mask = (const int*)d_in[4];
  const float* sentinel = (const float*)d_in[5];
  const float* W_enh = (const float*)d_in[6];  const float* b_enh = (const float*)d_in[7];
  const float* W_enm = (const float*)d_in[8];  const float* b_enm = (const float*)d_in[9];
  const float* W_elh = (const float*)d_in[10]; const float* b_elh = (const float*)d_in[11];
  const float* W_elm = (const float*)d_in[12]; const float* b_elm = (const float*)d_in[13];
  const float* ba_U = (const float*)d_in[14];  const float* ba_Wd = (const float*)d_in[15];
  const float* ba_We = (const float*)d_in[16]; const float* ba_b = (const float*)d_in[17];
  const float* lbl_U = (const float*)d_in[18]; const float* lbl_Wl = (const float*)d_in[19];
  const float* lbl_Wr = (const float*)d_in[20]; const float* lbl_b = (const float*)d_in[21];
  float* out = (float*)d_out;

  char* wsc = (char*)d_ws;
  size_t o = 0;
  auto alloc = [&](size_t n){ o = (o + 255) & ~(size_t)255; void* pp = wsc + o; o += n; return pp; };
  float* E     = (float*)alloc((size_t)TT*NE*4);
  float* T1    = (float*)alloc((size_t)TT*256*4);
  float* S     = (float*)alloc((size_t)BB*L1*L1*4);
  float* Wcat  = (float*)alloc((size_t)HH*NE*4);
  float* bcat  = (float*)alloc((size_t)NE*4);
  unsigned short* WtTp = (unsigned short*)alloc((size_t)128*KP*2);
  float* dvec  = (float*)alloc((size_t)TT*4);
  float* evec  = (float*)alloc((size_t)TT*4);
  int*   idx   = (int*)alloc((size_t)2*TT*4);
  int*   labbuf= (int*)alloc((size_t)TT*4);

  k_init<<<dim3(129), 256, 0, stream>>>(edge_heads, edge_labels, out, idx, labbuf);
  k_wcat<<<dim3(1200), 256, 0, stream>>>(W_enh, b_enh, W_enm, b_enm, W_elh, b_elh, W_elm, b_elm, Wcat, bcat);
  k_wtt<<<dim3(65, 128), 256, 0, stream>>>(lbl_U, lbl_Wl, lbl_Wr, WtTp);
  k_enc<<<dim3(257, 6), 256, 0, stream>>>(memory_bank, sentinel, Wcat, bcat, E);
  k_t1<<<dim3(257, 2), 256, 0, stream>>>(E, ba_U, T1);
  k_vecs<<<dim3(8208), 256, 0, stream>>>(E, ba_Wd, ba_We, ba_b, dvec, evec);
  k_ns<<<dim3(25, 64), 256, 0, stream>>>(T1, E, dvec, evec, S);
  k_nodecol<<<dim3(17, 64), 256, 0, stream>>>(S, edge_heads, mask, out, idx);
  k_label<<<dim3(256), 512, 0, stream>>>(E, WtTp, idx, labbuf, lbl_b, out);
}

// Round 6
// 1048.416 us; speedup vs baseline: 1.4720x; 1.0228x over previous
//
#include <hip/hip_runtime.h>
#include <hip/hip_bf16.h>

#define BB 64
#define LLEN 512
#define HH 400
#define L1 513
#define TT 32832      // BB*L1
#define NE 768        // enh(256)|enm(256)|elh(128)|elm(128)
#define KP 16640      // 16384 bilinear + 128 Wl + 128 Wr (phase-permuted)
#define PHW 4160      // per-phase k' width: 130 d-slices * 32

typedef __attribute__((ext_vector_type(4))) float f32x4;
typedef __attribute__((ext_vector_type(8))) short bf16x8;
typedef unsigned int u32;
typedef __attribute__((address_space(1))) const u32* gptr_t;
typedef __attribute__((address_space(3))) u32* sptr_t;

// round-to-nearest-even f32 -> bf16 (finite inputs)
__device__ inline unsigned short f2bf(float x){
  unsigned u = __float_as_uint(x);
  unsigned r = (u + 0x7fffu + ((u >> 16) & 1u)) >> 16;
  return (unsigned short)r;
}
// packed RNE f32x2 -> bf16x2 in one instruction (lo = a, hi = b)
__device__ inline unsigned cvtpk(float a, float b){
  unsigned r;
  asm("v_cvt_pk_bf16_f32 %0, %1, %2" : "=v"(r) : "v"(a), "v"(b));
  return r;
}
__device__ inline float bf2f(unsigned short h){
  return __uint_as_float(((unsigned)h) << 16);
}

// ---------------- init: labels1 output, gold gather idx, label buf, zero nll ----
__global__ __launch_bounds__(256) void k_init(const int* eh, const int* el, float* out,
                                              int* idx, int* labbuf){
  int t = blockIdx.x*256 + threadIdx.x;
  if (t < TT){
    int b = t / L1, m = t - b*L1;
    int lab = m ? el[b*LLEN + m - 1] : 0;
    int hd  = m ? eh[b*LLEN + m - 1] : 0;
    out[65536 + t] = (float)lab;
    labbuf[t] = lab;
    idx[t] = b*L1 + hd;
  }
  if (blockIdx.x == 0 && threadIdx.x < 2) out[98368 + threadIdx.x] = 0.f;
}

// ---------------- build concatenated encoder weights ----------------
__global__ __launch_bounds__(256) void k_wcat(const float* Wenh,const float* benh,
    const float* Wenm,const float* benm,const float* Welh,const float* belh,
    const float* Welm,const float* belm,float* Wcat,float* bcat){
  int g = blockIdx.x*256 + threadIdx.x;
  if (g < HH*NE){
    int k = g / NE, n = g - k*NE;
    float v;
    if (n < 256) v = Wenh[k*256 + n];
    else if (n < 512) v = Wenm[k*256 + n - 256];
    else if (n < 640) v = Welh[k*128 + n - 512];
    else v = Welm[k*128 + n - 640];
    Wcat[g] = v;
  }
  if (g < NE){
    float v;
    if (g < 256) v = benh[g];
    else if (g < 512) v = benm[g - 256];
    else if (g < 640) v = belh[g - 512];
    else v = belm[g - 640];
    bcat[g] = v;
  }
}

// ------------- build WtTp[n][k'] bf16, K phase-permuted: k' = p*4160 + d*32 + j,
// (p,d,j): d<128 -> U[n][d][32p+j]; d==128 -> Wl[n][32p+j]; d==129 -> Wr[n][32p+j]
__global__ __launch_bounds__(256) void k_wtt(const float* lblU, const float* Wl,
    const float* Wr, unsigned short* WtTp){
  int n = blockIdx.y;
  int kp = blockIdx.x*256 + threadIdx.x;
  if (kp >= KP) return;
  int p = kp / PHW; int q2 = kp - p*PHW; int dd = q2 >> 5; int j = q2 & 31; int e = p*32 + j;
  float v;
  if (dd < 128) v = lblU[(size_t)n*16384 + dd*128 + e];
  else if (dd == 128) v = Wl[n*128 + e];
  else v = Wr[n*128 + e];
  WtTp[(size_t)n*KP + kp] = f2bf(v);
}

#define INNER8(AS, BS) \
  _Pragma("unroll") \
  for (int kk = 0; kk < 8; kk++){ \
    float4 a0 = *(const float4*)&AS[kk][ty*8]; \
    float4 a1 = *(const float4*)&AS[kk][ty*8+4]; \
    float4 b0 = *(const float4*)&BS[kk][tx*8]; \
    float4 b1 = *(const float4*)&BS[kk][tx*8+4]; \
    float avv[8] = {a0.x,a0.y,a0.z,a0.w,a1.x,a1.y,a1.z,a1.w}; \
    float bvv[8] = {b0.x,b0.y,b0.z,b0.w,b1.x,b1.y,b1.z,b1.w}; \
    _Pragma("unroll") \
    for (int ii = 0; ii < 8; ii++) \
      _Pragma("unroll") \
      for (int jj = 0; jj < 8; jj++) \
        c_[ii][jj] += avv[ii]*bvv[jj]; \
  }

// ---------------- K1: E = elu([sentinel;mb] @ Wcat + bcat), fp32 128x128x8 tile ----
__global__ __launch_bounds__(256) void k_enc(const float* mb, const float* sent,
    const float* Wcat, const float* bcat, float* E){
  __shared__ float As[8][132];
  __shared__ float Bs[8][132];
  int tid = threadIdx.x, tx = tid & 15, ty = tid >> 4;
  int Mb = blockIdx.x * 128, n0 = blockIdx.y * 128;
  int ar = tid >> 1, akc = (tid & 1) * 4;
  int row = Mb + ar;
  bool aval = row < TT;
  const float* ap = sent;
  if (aval){
    int br = row / L1, mr = row - br*L1;
    if (mr) ap = mb + (size_t)(br*LLEN + mr - 1)*HH;
  }
  int bkr = tid >> 5, bnc = (tid & 31) * 4;
  float c_[8][8] = {};
  for (int k0 = 0; k0 < HH; k0 += 8){
    __syncthreads();
    float4 av = make_float4(0.f,0.f,0.f,0.f);
    if (aval) av = *(const float4*)(ap + k0 + akc);
    As[akc+0][ar] = av.x; As[akc+1][ar] = av.y; As[akc+2][ar] = av.z; As[akc+3][ar] = av.w;
    *(float4*)&Bs[bkr][bnc] = *(const float4*)(Wcat + (size_t)(k0 + bkr)*NE + n0 + bnc);
    __syncthreads();
    INNER8(As, Bs)
  }
  #pragma unroll
  for (int i = 0; i < 8; i++){
    int rr = Mb + ty*8 + i;
    if (rr < TT){
      float4 o0, o1;
      float t0v;
      t0v = c_[i][0] + bcat[n0+tx*8+0]; o0.x = t0v > 0.f ? t0v : expm1f(t0v);
      t0v = c_[i][1] + bcat[n0+tx*8+1]; o0.y = t0v > 0.f ? t0v : expm1f(t0v);
      t0v = c_[i][2] + bcat[n0+tx*8+2]; o0.z = t0v > 0.f ? t0v : expm1f(t0v);
      t0v = c_[i][3] + bcat[n0+tx*8+3]; o0.w = t0v > 0.f ? t0v : expm1f(t0v);
      t0v = c_[i][4] + bcat[n0+tx*8+4]; o1.x = t0v > 0.f ? t0v : expm1f(t0v);
      t0v = c_[i][5] + bcat[n0+tx*8+5]; o1.y = t0v > 0.f ? t0v : expm1f(t0v);
      t0v = c_[i][6] + bcat[n0+tx*8+6]; o1.z = t0v > 0.f ? t0v : expm1f(t0v);
      t0v = c_[i][7] + bcat[n0+tx*8+7]; o1.w = t0v > 0.f ? t0v : expm1f(t0v);
      *(float4*)&E[(size_t)rr*NE + n0 + tx*8] = o0;
      *(float4*)&E[(size_t)rr*NE + n0 + tx*8 + 4] = o1;
    }
  }
}

// ---------------- K2: T1 = enh @ ba_U ----------------
__global__ __launch_bounds__(256) void k_t1(const float* E, const float* baU, float* T1){
  __shared__ float As[8][132];
  __shared__ float Bs[8][132];
  int tid = threadIdx.x, tx = tid & 15, ty = tid >> 4;
  int Mb = blockIdx.x * 128, n0 = blockIdx.y * 128;
  int ar = tid >> 1, akc = (tid & 1) * 4;
  int row = Mb + ar;
  bool aval = row < TT;
  const float* ap = E + (size_t)(aval ? row : 0)*NE;
  int bkr = tid >> 5, bnc = (tid & 31) * 4;
  float c_[8][8] = {};
  for (int k0 = 0; k0 < 256; k0 += 8){
    __syncthreads();
    float4 av = make_float4(0.f,0.f,0.f,0.f);
    if (aval) av = *(const float4*)(ap + k0 + akc);
    As[akc+0][ar] = av.x; As[akc+1][ar] = av.y; As[akc+2][ar] = av.z; As[akc+3][ar] = av.w;
    *(float4*)&Bs[bkr][bnc] = *(const float4*)(baU + (size_t)(k0 + bkr)*256 + n0 + bnc);
    __syncthreads();
    INNER8(As, Bs)
  }
  #pragma unroll
  for (int i = 0; i < 8; i++){
    int rr = Mb + ty*8 + i;
    if (rr < TT){
      float4 o0 = {c_[i][0],c_[i][1],c_[i][2],c_[i][3]};
      float4 o1 = {c_[i][4],c_[i][5],c_[i][6],c_[i][7]};
      *(float4*)&T1[(size_t)rr*256 + n0 + tx*8] = o0;
      *(float4*)&T1[(size_t)rr*256 + n0 + tx*8 + 4] = o1;
    }
  }
}

// ---------------- K2b: dvec = enh@ba_Wd + ba_b ; evec = enm@ba_We ----------------
__global__ __launch_bounds__(256) void k_vecs(const float* E, const float* Wd,
    const float* We, const float* bab, float* dvec, float* evec){
  int w = threadIdx.x >> 6, lane = threadIdx.x & 63;
  int t = blockIdx.x*4 + w;
  const float* enh = E + (size_t)t*NE;
  const float* enm = enh + 256;
  float sd = 0.f, se = 0.f;
  for (int l = lane; l < 256; l += 64){ sd += enh[l]*Wd[l]; se += enm[l]*We[l]; }
  for (int o = 1; o < 64; o <<= 1){ sd += __shfl_xor(sd, o, 64); se += __shfl_xor(se, o, 64); }
  if (lane == 0){ dvec[t] = sd + bab[0]; evec[t] = se; }
}

// ---------------- K3a: S[b,h,m] = T1[b,h,:]·enm[b,m,:] + dvec[h] + evec[m] ----------
__global__ __launch_bounds__(256) void k_ns(const float* T1, const float* E,
    const float* dvec, const float* evec, float* S){
  __shared__ float As[8][132];
  __shared__ float Bs[8][132];
  int tid = threadIdx.x, tx = tid & 15, ty = tid >> 4;
  int b = blockIdx.y;
  int tm = blockIdx.x / 5, tn = blockIdx.x - tm*5;
  int Mb = tm*128, n0 = tn*128;
  int ar = tid >> 1, akc = (tid & 1) * 4;
  int hrow = Mb + ar; bool aval = hrow < L1;
  const float* ap = T1 + ((size_t)b*L1 + (aval ? hrow : 0))*256;
  int mrow = n0 + ar; bool bval = mrow < L1;
  const float* bp = E + ((size_t)b*L1 + (bval ? mrow : 0))*NE + 256;
  float c_[8][8] = {};
  for (int k0 = 0; k0 < 256; k0 += 8){
    __syncthreads();
    float4 av = make_float4(0.f,0.f,0.f,0.f);
    float4 bv2 = make_float4(0.f,0.f,0.f,0.f);
    if (aval) av = *(const float4*)(ap + k0 + akc);
    if (bval) bv2 = *(const float4*)(bp + k0 + akc);
    As[akc+0][ar] = av.x; As[akc+1][ar] = av.y; As[akc+2][ar] = av.z; As[akc+3][ar] = av.w;
    Bs[akc+0][ar] = bv2.x; Bs[akc+1][ar] = bv2.y; Bs[akc+2][ar] = bv2.z; Bs[akc+3][ar] = bv2.w;
    __syncthreads();
    INNER8(As, Bs)
  }
  float dr[8], er[8];
  #pragma unroll
  for (int i = 0; i < 8; i++){ int h = Mb + ty*8 + i; dr[i] = (h < L1) ? dvec[b*L1 + h] : 0.f; }
  #pragma unroll
  for (int j = 0; j < 8; j++){ int m = n0 + tx*8 + j; er[j] = (m < L1) ? evec[b*L1 + m] : 0.f; }
  float* Sb = S + (size_t)b*L1*L1;
  #pragma unroll
  for (int i = 0; i < 8; i++){
    int h = Mb + ty*8 + i;
    if (h < L1){
      #pragma unroll
      for (int j = 0; j < 8; j++){
        int m = n0 + tx*8 + j;
        if (m < L1) Sb[(size_t)h*L1 + m] = c_[i][j] + dr[i] + er[j];
      }
    }
  }
}

// --------- K3b: per-column log-softmax(gold) + node_nll + argmax decode -----------
__global__ __launch_bounds__(256) void k_nodecol(const float* S, const int* eh,
    const int* mask, float* out, int* idx){
  int b = blockIdx.y, mt = blockIdx.x;
  __shared__ float msk[L1];
  __shared__ float rM[8][32], rS[8][32], rG[8][32], rB[8][32];
  __shared__ int rH[8][32];
  __shared__ float npart[32];
  int tid = threadIdx.x; int c = tid & 31, r = tid >> 5;
  for (int h = tid; h < L1; h += 256) msk[h] = h ? (float)mask[b*LLEN + h - 1] : 0.f;
  __syncthreads();
  int m = mt*32 + c; bool valid = m < L1; int mc = valid ? m : (L1-1);
  float maskm = msk[mc];
  int gold = 0; if (valid && m) gold = eh[b*LLEN + m - 1];
  const float* Sb = S + (size_t)b*L1*L1;
  float Mx = -3.4e38f, Sm = 0.f, G = 0.f, Bv = -3.4e38f; int Bh = 0;
  for (int h = r; h < L1; h += 8){
    float s = Sb[(size_t)h*L1 + mc];
    float adj = s + ((msk[h] + maskm) > 1.5f ? 0.69314718055994531f : 0.f);
    float nm = fmaxf(Mx, adj);
    Sm = Sm * expf(Mx - nm) + expf(adj - nm);
    Mx = nm;
    if (h == gold) G = adj;
    float dv = (h == m) ? -3.4e38f : (s + (msk[h] > 0.5f ? 0.f : -1e8f));
    if (dv > Bv){ Bv = dv; Bh = h; }
  }
  rM[r][c] = Mx; rS[r][c] = Sm; rG[r][c] = G; rB[r][c] = Bv; rH[r][c] = Bh;
  __syncthreads();
  if (r == 0){
    float M0 = rM[0][c], S0 = rS[0][c], G0 = rG[0][c], B0 = rB[0][c]; int H0 = rH[0][c];
    for (int rr = 1; rr < 8; rr++){
      float m2 = rM[rr][c], s2 = rS[rr][c];
      float nm = fmaxf(M0, m2);
      S0 = S0*expf(M0 - nm) + s2*expf(m2 - nm); M0 = nm;
      G0 += rG[rr][c];
      float b2 = rB[rr][c]; int h2 = rH[rr][c];
      if (b2 > B0 || (b2 == B0 && h2 < H0)){ B0 = b2; H0 = h2; }
    }
    float nll = 0.f;
    if (valid && m >= 1) nll = (M0 + logf(S0)) - G0;
    npart[c] = nll;
    if (valid){
      idx[TT + b*L1 + m] = b*L1 + H0;
      if (m >= 1) out[b*LLEN + m - 1] = (float)H0;
    }
  }
  __syncthreads();
  if (tid == 0){
    float ssum = 0.f;
    for (int i2 = 0; i2 < 32; i2++) ssum += npart[i2];
    atomicAdd(out + 98368, ssum);
  }
}

// --------- K4: label bilinear as big-K MFMA GEMM, P generated on the fly ----------
// v8: v7 + 2 slices per barrier (130 iters). Per wave per iter: 16 ds_read_b128,
//     64 MFMA -> doubles MFMA work per fixed per-barrier overhead. Bst = 4 bufs
//     x 2 K-halves (64KB); at iter u stage slices 2u+2,2u+3 into the buffer pair
//     consumed at iter u-1 (post-barrier -> race-free); vmcnt(0) wait has a full
//     iteration (>=2500cy) of slack vs <=900cy load latency.
__global__ __launch_bounds__(512, 1) void k_label(const float* E, const unsigned short* WtTp,
    const int* idx, const int* labbuf, const float* lblb, float* out){
  __shared__ __align__(16) unsigned char Bst[8*8192];   // [2 halves][4 bufs][8192]
  __shared__ __align__(16) unsigned int xls[256*65];    // 256 tok x 130 bf16, stride 65 u32
  int tid = threadIdx.x;
  int w = tid >> 6, lane = tid & 63, c = lane & 15, q = lane >> 4;
  int wgrp = w & 3, khalf = w >> 2;
  int bx = blockIdx.x;
  bool pred = bx >= 128;
  int q0 = (bx & 127) * 256;        // compact index within pass: q -> (b=q>>9, m=(q&511)+1)
  int ibase = pred ? TT : 0;

  const char* gW = (const char*)WtTp;
  // this thread's fixed B-chunk: chunk f holds WtTp[16*(f>>6)+(f&15)][s*32+((f>>4)&3)*8 ..+8)
  int f = tid;
  int bn = ((f >> 6) << 4) + (f & 15);
  int bkq = (f >> 4) & 3;
  const char* bsrc0 = gW + (size_t)bn*(KP*2) + (size_t)bkq*16;
  unsigned char* BbA = Bst;            // [4][8192] for K-half 0
  unsigned char* BbB = Bst + 4*8192;   // [4][8192] for K-half 1
  auto stage2 = [&](int s){
    __builtin_amdgcn_global_load_lds((gptr_t)(bsrc0 + (size_t)s*64),
        (sptr_t)(BbA + (s & 3)*8192 + f*16), 16, 0, 0);
    __builtin_amdgcn_global_load_lds((gptr_t)(bsrc0 + (size_t)(260 + s)*64),
        (sptr_t)(BbB + (s & 3)*8192 + f*16), 16, 0, 0);
  };
  stage2(0); stage2(1);

  // ---- stage gathered x rows (elh[g]) into LDS as bf16 (1 half-row/thread) ----
  {
    int tok = tid >> 1, half = tid & 1;
    int qq = q0 + tok;
    int trow = (qq >> 9)*L1 + (qq & 511) + 1;
    int g = idx[ibase + trow];
    const float* xr = E + (size_t)g*NE + 512 + half*64;
    unsigned* dstx = &xls[tok*65 + half*32];
    #pragma unroll
    for (int j = 0; j < 16; j++){
      float4 v = *(const float4*)(xr + j*4);
      dstx[2*j]   = cvtpk(v.x, v.y);
      dstx[2*j+1] = cvtpk(v.z, v.w);
    }
  }

  const float *yvb[4], *xvb[4];
  int tokl[4];
  #pragma unroll
  for (int ms = 0; ms < 4; ms++){
    int tl = (wgrp*4 + ms)*16 + c;
    tokl[ms] = tl;
    int qq = q0 + tl;
    int trow = (qq >> 9)*L1 + (qq & 511) + 1;
    int g = idx[ibase + trow];
    yvb[ms] = E + (size_t)trow*NE + 640 + 8*q;   // elm row, this lane's q-offset
    xvb[ms] = E + (size_t)g*NE + 512 + 8*q;      // elh row (gathered)
  }
  f32x4 acc[4][8];
  #pragma unroll
  for (int ms = 0; ms < 4; ms++)
    #pragma unroll
    for (int ns = 0; ns < 8; ns++){ acc[ms][ns][0]=0.f; acc[ms][ns][1]=0.f; acc[ms][ns][2]=0.f; acc[ms][ns][3]=0.f; }

  __syncthreads();   // xls visible; full drain of prologue stages (once)

  const unsigned short* xsh = (const unsigned short*)xls;
  float xs0[4], xs1[4];
  #pragma unroll
  for (int ms = 0; ms < 4; ms++){
    xs0[ms] = bf2f(xsh[tokl[ms]*130]);
    xs1[ms] = bf2f(xsh[tokl[ms]*130 + 1]);
  }

  float yreg[4][8];
  for (int u = 0; u < 130; u++){
    if (u) { asm volatile("s_waitcnt vmcnt(0)" ::: "memory"); }
    __builtin_amdgcn_sched_barrier(0);
    __builtin_amdgcn_s_barrier();
    __builtin_amdgcn_sched_barrier(0);
    // stage the pair for iter u+1 into the bufs consumed at iter u-1 (race-free)
    if (2*u + 2 < 260){ stage2(2*u + 2); stage2(2*u + 3); }
    int ph = (u >= 65);
    int d0 = 2*u - ph*130;
    if (d0 == 0){
      int e0 = (khalf*2 + ph) * 32;
      #pragma unroll
      for (int ms = 0; ms < 4; ms++){
        float4 v0 = *(const float4*)(yvb[ms] + e0);
        float4 v1 = *(const float4*)(yvb[ms] + e0 + 4);
        yreg[ms][0]=v0.x; yreg[ms][1]=v0.y; yreg[ms][2]=v0.z; yreg[ms][3]=v0.w;
        yreg[ms][4]=v1.x; yreg[ms][5]=v1.y; yreg[ms][6]=v1.z; yreg[ms][7]=v1.w;
      }
    }
    bf16x8 afr0[4], afr1[4];
    if (d0 < 128){
      #pragma unroll
      for (int ms = 0; ms < 4; ms++){
        float a0 = xs0[ms], a1 = xs1[ms];
        union { unsigned u[4]; bf16x8 v; } u0, u1;
        u0.u[0] = cvtpk(a0*yreg[ms][0], a0*yreg[ms][1]);
        u0.u[1] = cvtpk(a0*yreg[ms][2], a0*yreg[ms][3]);
        u0.u[2] = cvtpk(a0*yreg[ms][4], a0*yreg[ms][5]);
        u0.u[3] = cvtpk(a0*yreg[ms][6], a0*yreg[ms][7]);
        u1.u[0] = cvtpk(a1*yreg[ms][0], a1*yreg[ms][1]);
        u1.u[1] = cvtpk(a1*yreg[ms][2], a1*yreg[ms][3]);
        u1.u[2] = cvtpk(a1*yreg[ms][4], a1*yreg[ms][5]);
        u1.u[3] = cvtpk(a1*yreg[ms][6], a1*yreg[ms][7]);
        afr0[ms] = u0.v; afr1[ms] = u1.v;
      }
    } else {
      // u==64 or u==129: slice pair (d=128, d=129) = (x-frag, y-frag)
      int e0 = (khalf*2 + ph) * 32;
      #pragma unroll
      for (int ms = 0; ms < 4; ms++){
        float4 u0f = *(const float4*)(xvb[ms] + e0);
        float4 u1f = *(const float4*)(xvb[ms] + e0 + 4);
        union { unsigned u[4]; bf16x8 v; } ux, uy;
        ux.u[0]=cvtpk(u0f.x,u0f.y); ux.u[1]=cvtpk(u0f.z,u0f.w);
        ux.u[2]=cvtpk(u1f.x,u1f.y); ux.u[3]=cvtpk(u1f.z,u1f.w);
        uy.u[0]=cvtpk(yreg[ms][0],yreg[ms][1]); uy.u[1]=cvtpk(yreg[ms][2],yreg[ms][3]);
        uy.u[2]=cvtpk(yreg[ms][4],yreg[ms][5]); uy.u[3]=cvtpk(yreg[ms][6],yreg[ms][7]);
        afr0[ms] = ux.v; afr1[ms] = uy.v;
      }
    }
    // prefetch next iter's x pair (d0+2,d0+3; wraps to 0,1 across phase/specials)
    {
      int nd0 = 2*(u + 1) - ((u + 1 >= 65) ? 130 : 0);
      if (nd0 >= 128) nd0 = 0;
      #pragma unroll
      for (int ms = 0; ms < 4; ms++){
        xs0[ms] = bf2f(xsh[tokl[ms]*130 + nd0]);
        xs1[ms] = bf2f(xsh[tokl[ms]*130 + nd0 + 1]);
      }
    }
    const char* hb = (const char*)(khalf ? BbB : BbA);
    const char* bs0 = hb + ((2*u) & 3)*8192;
    const char* bs1 = hb + ((2*u + 1) & 3)*8192;
    #pragma unroll
    for (int ns = 0; ns < 8; ns++){
      bf16x8 bfr0 = *(const bf16x8*)(bs0 + ns*1024 + lane*16);
      bf16x8 bfr1 = *(const bf16x8*)(bs1 + ns*1024 + lane*16);
      #pragma unroll
      for (int ms = 0; ms < 4; ms++){
        acc[ms][ns] = __builtin_amdgcn_mfma_f32_16x16x32_bf16(afr0[ms], bfr0, acc[ms][ns], 0, 0, 0);
        acc[ms][ns] = __builtin_amdgcn_mfma_f32_16x16x32_bf16(afr1[ms], bfr1, acc[ms][ns], 0, 0, 0);
      }
    }
  }

  // ---- combine K-halves through LDS (reuses xls region), 4 rounds of 32KB ----
  // slot swizzled by (ns+lane)&7: banks spread 8-way instead of 32-way.
  __syncthreads();
  float* cmb = (float*)xls;
  #pragma unroll
  for (int ms = 0; ms < 4; ms++){
    if (khalf == 1){
      #pragma unroll
      for (int ns = 0; ns < 8; ns++)
        *(f32x4*)&cmb[((wgrp*64 + lane)*8 + ((ns + lane) & 7))*4] = acc[ms][ns];
    }
    __syncthreads();
    if (khalf == 0){
      #pragma unroll
      for (int ns = 0; ns < 8; ns++){
        f32x4 t = *(const f32x4*)&cmb[((wgrp*64 + lane)*8 + ((ns + lane) & 7))*4];
        acc[ms][ns][0] += t[0]; acc[ms][ns][1] += t[1];
        acc[ms][ns][2] += t[2]; acc[ms][ns][3] += t[3];
      }
    }
    __syncthreads();
  }
  if (khalf == 1) return;   // no barriers past this point

  // ---- epilogue (khalf0 waves): C row = token (4q+i), col n = 16*ns + c ----
  float bv[8];
  #pragma unroll
  for (int ns = 0; ns < 8; ns++) bv[ns] = lblb[ns*16 + c];
  float part = 0.f;
  #pragma unroll
  for (int ms = 0; ms < 4; ms++){
    int tb = (wgrp*4 + ms)*16 + 4*q;       // local token base
    float mx[4] = {-3.4e38f, -3.4e38f, -3.4e38f, -3.4e38f};
    #pragma unroll
    for (int ns = 0; ns < 8; ns++)
      #pragma unroll
      for (int i = 0; i < 4; i++){
        float v = acc[ms][ns][i] + bv[ns];
        mx[i] = fmaxf(mx[i], v);
      }
    #pragma unroll
    for (int o = 1; o < 16; o <<= 1)
      #pragma unroll
      for (int i = 0; i < 4; i++) mx[i] = fmaxf(mx[i], __shfl_xor(mx[i], o, 64));
    if (!pred){
      int lab[4];
      #pragma unroll
      for (int i = 0; i < 4; i++){
        int qq = q0 + tb + i;
        int trow = (qq >> 9)*L1 + (qq & 511) + 1;
        lab[i] = labbuf[trow];
      }
      float se[4] = {0.f,0.f,0.f,0.f}, gp[4] = {0.f,0.f,0.f,0.f};
      #pragma unroll
      for (int ns = 0; ns < 8; ns++)
        #pragma unroll
        for (int i = 0; i < 4; i++){
          float v = acc[ms][ns][i] + bv[ns];
          se[i] += expf(v - mx[i]);
          if (ns*16 + c == lab[i]) gp[i] += v;
        }
      #pragma unroll
      for (int o = 1; o < 16; o <<= 1)
        #pragma unroll
        for (int i = 0; i < 4; i++){ se[i] += __shfl_xor(se[i], o, 64); gp[i] += __shfl_xor(gp[i], o, 64); }
      if (c == 0){
        #pragma unroll
        for (int i = 0; i < 4; i++) part += mx[i] + logf(se[i]) - gp[i];
      }
    } else {
      if (c == 0){
        #pragma unroll
        for (int i = 0; i < 4; i++)
          out[32768 + q0 + tb + i] = mx[i];   // pred slot = 32768 + compact q
      }
    }
  }
  if (!pred){
    for (int o = 1; o < 64; o <<= 1) part += __shfl_xor(part, o, 64);
    if (lane == 0) atomicAdd(out + 98369, part);
  }
}

extern "C" void kernel_launch(void* const* d_in, const int* in_sizes, int n_in,
                              void* d_out, int out_size, void* d_ws, size_t ws_size,
                              hipStream_t stream){
  const float* memory_bank = (const float*)d_in[0];
  const int* edge_heads = (const int*)d_in[1];
  const int* edge_labels = (const int*)d_in[2];
  const int* mask = (const int*)d_in[4];
  const float* sentinel = (const float*)d_in[5];
  const float* W_enh = (const float*)d_in[6];  const float* b_enh = (const float*)d_in[7];
  const float* W_enm = (const float*)d_in[8];  const float* b_enm = (const float*)d_in[9];
  const float* W_elh = (const float*)d_in[10]; const float* b_elh = (const float*)d_in[11];
  const float* W_elm = (const float*)d_in[12]; const float* b_elm = (const float*)d_in[13];
  const float* ba_U = (const float*)d_in[14];  const float* ba_Wd = (const float*)d_in[15];
  const float* ba_We = (const float*)d_in[16]; const float* ba_b = (const float*)d_in[17];
  const float* lbl_U = (const float*)d_in[18]; const float* lbl_Wl = (const float*)d_in[19];
  const float* lbl_Wr = (const float*)d_in[20]; const float* lbl_b = (const float*)d_in[21];
  float* out = (float*)d_out;

  char* wsc = (char*)d_ws;
  size_t o = 0;
  auto alloc = [&](size_t n){ o = (o + 255) & ~(size_t)255; void* pp = wsc + o; o += n; return pp; };
  float* E     = (float*)alloc((size_t)TT*NE*4);
  float* T1    = (float*)alloc((size_t)TT*256*4);
  float* S     = (float*)alloc((size_t)BB*L1*L1*4);
  float* Wcat  = (float*)alloc((size_t)HH*NE*4);
  float* bcat  = (float*)alloc((size_t)NE*4);
  unsigned short* WtTp = (unsigned short*)alloc((size_t)128*KP*2);
  float* dvec  = (float*)alloc((size_t)TT*4);
  float* evec  = (float*)alloc((size_t)TT*4);
  int*   idx   = (int*)alloc((size_t)2*TT*4);
  int*   labbuf= (int*)alloc((size_t)TT*4);

  k_init<<<dim3(129), 256, 0, stream>>>(edge_heads, edge_labels, out, idx, labbuf);
  k_wcat<<<dim3(1200), 256, 0, stream>>>(W_enh, b_enh, W_enm, b_enm, W_elh, b_elh, W_elm, b_elm, Wcat, bcat);
  k_wtt<<<dim3(65, 128), 256, 0, stream>>>(lbl_U, lbl_Wl, lbl_Wr, WtTp);
  k_enc<<<dim3(257, 6), 256, 0, stream>>>(memory_bank, sentinel, Wcat, bcat, E);
  k_t1<<<dim3(257, 2), 256, 0, stream>>>(E, ba_U, T1);
  k_vecs<<<dim3(8208), 256, 0, stream>>>(E, ba_Wd, ba_We, ba_b, dvec, evec);
  k_ns<<<dim3(25, 64), 256, 0, stream>>>(T1, E, dvec, evec, S);
  k_nodecol<<<dim3(17, 64), 256, 0, stream>>>(S, edge_heads, mask, out, idx);
  k_label<<<dim3(256), 512, 0, stream>>>(E, WtTp, idx, labbuf, lbl_b, out);
}

// Round 7
// 840.101 us; speedup vs baseline: 1.8370x; 1.2480x over previous
//
#include <hip/hip_runtime.h>
#include <hip/hip_bf16.h>

#define BB 64
#define LLEN 512
#define HH 400
#define L1 513
#define TT 32832      // BB*L1
#define NE 768        // enh(256)|enm(256)|elh(128)|elm(128)
#define KP 16640      // 16384 bilinear + 128 Wl + 128 Wr (phase-permuted)
#define PHW 4160      // per-phase k' width: 130 d-slices * 32
#define KPAD 416      // k_encm padded K (400 -> 13 slices of 32)

typedef __attribute__((ext_vector_type(4))) float f32x4;
typedef __attribute__((ext_vector_type(8))) short bf16x8;
typedef unsigned int u32;
typedef __attribute__((address_space(1))) const u32* gptr_t;
typedef __attribute__((address_space(3))) u32* sptr_t;

// round-to-nearest-even f32 -> bf16 (finite inputs)
__device__ inline unsigned short f2bf(float x){
  unsigned u = __float_as_uint(x);
  unsigned r = (u + 0x7fffu + ((u >> 16) & 1u)) >> 16;
  return (unsigned short)r;
}
// packed RNE f32x2 -> bf16x2 in one instruction (lo = a, hi = b)
__device__ inline unsigned cvtpk(float a, float b){
  unsigned r;
  asm("v_cvt_pk_bf16_f32 %0, %1, %2" : "=v"(r) : "v"(a), "v"(b));
  return r;
}
__device__ inline float bf2f(unsigned short h){
  return __uint_as_float(((unsigned)h) << 16);
}

// ---------------- init: labels1 output, gold gather idx, label buf, zero nll ----
__global__ __launch_bounds__(256) void k_init(const int* eh, const int* el, float* out,
                                              int* idx, int* labbuf){
  int t = blockIdx.x*256 + threadIdx.x;
  if (t < TT){
    int b = t / L1, m = t - b*L1;
    int lab = m ? el[b*LLEN + m - 1] : 0;
    int hd  = m ? eh[b*LLEN + m - 1] : 0;
    out[65536 + t] = (float)lab;
    labbuf[t] = lab;
    idx[t] = b*L1 + hd;
  }
  if (blockIdx.x == 0 && threadIdx.x < 2) out[98368 + threadIdx.x] = 0.f;
}

// -------- build split-bf16 encoder weights WH/WL [n=768][k=416] + bcat --------
__global__ __launch_bounds__(256) void k_wcat(const float* Wenh,const float* benh,
    const float* Wenm,const float* benm,const float* Welh,const float* belh,
    const float* Welm,const float* belm, unsigned short* WH, unsigned short* WL,
    float* bcat){
  int g = blockIdx.x*256 + threadIdx.x;
  if (g < NE*KPAD){
    int n = g / KPAD, k = g - n*KPAD;
    float v = 0.f;
    if (k < HH){
      if (n < 256) v = Wenh[k*256 + n];
      else if (n < 512) v = Wenm[k*256 + n - 256];
      else if (n < 640) v = Welh[k*128 + n - 512];
      else v = Welm[k*128 + n - 640];
    }
    unsigned short h = f2bf(v);
    WH[g] = h;
    WL[g] = f2bf(v - bf2f(h));
  }
  if (g < NE){
    float v;
    if (g < 256) v = benh[g];
    else if (g < 512) v = benm[g - 256];
    else if (g < 640) v = belh[g - 512];
    else v = belm[g - 640];
    bcat[g] = v;
  }
}

// ------------- build WtTp[n][k'] bf16, K phase-permuted: k' = p*4160 + d*32 + j,
// (p,d,j): d<128 -> U[n][d][32p+j]; d==128 -> Wl[n][32p+j]; d==129 -> Wr[n][32p+j]
__global__ __launch_bounds__(256) void k_wtt(const float* lblU, const float* Wl,
    const float* Wr, unsigned short* WtTp){
  int n = blockIdx.y;
  int kp = blockIdx.x*256 + threadIdx.x;
  if (kp >= KP) return;
  int p = kp / PHW; int q2 = kp - p*PHW; int dd = q2 >> 5; int j = q2 & 31; int e = p*32 + j;
  float v;
  if (dd < 128) v = lblU[(size_t)n*16384 + dd*128 + e];
  else if (dd == 128) v = Wl[n*128 + e];
  else v = Wr[n*128 + e];
  WtTp[(size_t)n*KP + kp] = f2bf(v);
}

#define INNER8(AS, BS) \
  _Pragma("unroll") \
  for (int kk = 0; kk < 8; kk++){ \
    float4 a0 = *(const float4*)&AS[kk][ty*8]; \
    float4 a1 = *(const float4*)&AS[kk][ty*8+4]; \
    float4 b0 = *(const float4*)&BS[kk][tx*8]; \
    float4 b1 = *(const float4*)&BS[kk][tx*8+4]; \
    float avv[8] = {a0.x,a0.y,a0.z,a0.w,a1.x,a1.y,a1.z,a1.w}; \
    float bvv[8] = {b0.x,b0.y,b0.z,b0.w,b1.x,b1.y,b1.z,b1.w}; \
    _Pragma("unroll") \
    for (int ii = 0; ii < 8; ii++) \
      _Pragma("unroll") \
      for (int jj = 0; jj < 8; jj++) \
        c_[ii][jj] += avv[ii]*bvv[jj]; \
  }

// ---- K1 (v9): E = elu([sentinel;mb] @ Wcat + bcat) via split-bf16 MFMA ----
// A = Ah + Al (bf16 hi/lo), B likewise (precomputed WH/WL). acc += Ah*Bh +
// Ah*Bl + Al*Bh (Al*Bl dropped, ~2^-18 rel err). 8 waves: wave w owns 32
// tokens x 128 cols; 13 K-slices, double-buffered 16KB B staging.
__global__ __launch_bounds__(512) void k_encm(const float* mb, const float* sent,
    const unsigned short* WH, const unsigned short* WL, const float* bcat, float* E){
  __shared__ __align__(16) unsigned char Bst[2][2][8192];   // [buf][H/L][8KB]
  int tid = threadIdx.x, w = tid >> 6, lane = tid & 63, c = lane & 15, q = lane >> 4;
  int tb0 = blockIdx.x*256 + w*32;    // wave's 32 tokens
  int n0 = blockIdx.y*128;

  const float* ap[2];
  #pragma unroll
  for (int ms = 0; ms < 2; ms++){
    int row = tb0 + ms*16 + c;
    const float* p = sent;
    if (row < TT){
      int br = row / L1, mr = row - br*L1;
      if (mr) p = mb + (size_t)(br*LLEN + mr - 1)*HH;
    }
    ap[ms] = p;
  }

  int f = tid;
  int bn = ((f >> 6) << 4) + (f & 15);
  int bkq = (f >> 4) & 3;
  const char* srcH = (const char*)WH + (size_t)(n0 + bn)*(KPAD*2) + bkq*16;
  const char* srcL = (const char*)WL + (size_t)(n0 + bn)*(KPAD*2) + bkq*16;
  auto stageB = [&](int s){
    __builtin_amdgcn_global_load_lds((gptr_t)(srcH + (size_t)s*64),
        (sptr_t)(&Bst[s & 1][0][f*16]), 16, 0, 0);
    __builtin_amdgcn_global_load_lds((gptr_t)(srcL + (size_t)s*64),
        (sptr_t)(&Bst[s & 1][1][f*16]), 16, 0, 0);
  };

  float4 a0[2], a1[2];
  auto loadA = [&](int s){
    #pragma unroll
    for (int ms = 0; ms < 2; ms++){
      int k = s*32 + q*8;
      float4 v0 = make_float4(0.f,0.f,0.f,0.f), v1 = v0;
      if (k < HH){ v0 = *(const float4*)(ap[ms] + k); v1 = *(const float4*)(ap[ms] + k + 4); }
      a0[ms] = v0; a1[ms] = v1;
    }
  };
  stageB(0);
  loadA(0);

  f32x4 acc[2][8];
  #pragma unroll
  for (int ms = 0; ms < 2; ms++)
    #pragma unroll
    for (int ns = 0; ns < 8; ns++){ acc[ms][ns][0]=0.f; acc[ms][ns][1]=0.f; acc[ms][ns][2]=0.f; acc[ms][ns][3]=0.f; }

  for (int s = 0; s < 13; s++){
    asm volatile("s_waitcnt vmcnt(0)" ::: "memory");
    __builtin_amdgcn_sched_barrier(0);
    __builtin_amdgcn_s_barrier();
    __builtin_amdgcn_sched_barrier(0);
    if (s + 1 < 13) stageB(s + 1);
    bf16x8 Ah[2], Al[2];
    #pragma unroll
    for (int ms = 0; ms < 2; ms++){
      float v[8] = {a0[ms].x,a0[ms].y,a0[ms].z,a0[ms].w,a1[ms].x,a1[ms].y,a1[ms].z,a1[ms].w};
      union { unsigned u[4]; bf16x8 b; } uh, ul;
      float r[8];
      #pragma unroll
      for (int j = 0; j < 4; j++){
        unsigned h = cvtpk(v[2*j], v[2*j+1]);
        uh.u[j] = h;
        r[2*j]   = v[2*j]   - __uint_as_float((h & 0xffffu) << 16);
        r[2*j+1] = v[2*j+1] - __uint_as_float((h >> 16) << 16);
      }
      #pragma unroll
      for (int j = 0; j < 4; j++) ul.u[j] = cvtpk(r[2*j], r[2*j+1]);
      Ah[ms] = uh.b; Al[ms] = ul.b;
    }
    if (s + 1 < 13) loadA(s + 1);   // prefetch next slice's A under the MFMAs
    const char* bh = (const char*)&Bst[s & 1][0][0];
    const char* bl = (const char*)&Bst[s & 1][1][0];
    #pragma unroll
    for (int ns = 0; ns < 8; ns++){
      bf16x8 BH = *(const bf16x8*)(bh + ns*1024 + lane*16);
      bf16x8 BL = *(const bf16x8*)(bl + ns*1024 + lane*16);
      #pragma unroll
      for (int ms = 0; ms < 2; ms++){
        acc[ms][ns] = __builtin_amdgcn_mfma_f32_16x16x32_bf16(Ah[ms], BH, acc[ms][ns], 0, 0, 0);
        acc[ms][ns] = __builtin_amdgcn_mfma_f32_16x16x32_bf16(Ah[ms], BL, acc[ms][ns], 0, 0, 0);
        acc[ms][ns] = __builtin_amdgcn_mfma_f32_16x16x32_bf16(Al[ms], BH, acc[ms][ns], 0, 0, 0);
      }
    }
  }

  // epilogue: row = tb0 + ms*16 + 4q + i, col = n0 + 16*ns + c; bias + elu
  float bvv[8];
  #pragma unroll
  for (int ns = 0; ns < 8; ns++) bvv[ns] = bcat[n0 + ns*16 + c];
  #pragma unroll
  for (int ms = 0; ms < 2; ms++){
    #pragma unroll
    for (int i = 0; i < 4; i++){
      int row = tb0 + ms*16 + 4*q + i;
      if (row < TT){
        #pragma unroll
        for (int ns = 0; ns < 8; ns++){
          float t = acc[ms][ns][i] + bvv[ns];
          E[(size_t)row*NE + n0 + ns*16 + c] = t > 0.f ? t : expm1f(t);
        }
      }
    }
  }
}

// ---------------- K2: T1 = enh @ ba_U ----------------
__global__ __launch_bounds__(256) void k_t1(const float* E, const float* baU, float* T1){
  __shared__ float As[8][132];
  __shared__ float Bs[8][132];
  int tid = threadIdx.x, tx = tid & 15, ty = tid >> 4;
  int Mb = blockIdx.x * 128, n0 = blockIdx.y * 128;
  int ar = tid >> 1, akc = (tid & 1) * 4;
  int row = Mb + ar;
  bool aval = row < TT;
  const float* ap = E + (size_t)(aval ? row : 0)*NE;
  int bkr = tid >> 5, bnc = (tid & 31) * 4;
  float c_[8][8] = {};
  for (int k0 = 0; k0 < 256; k0 += 8){
    __syncthreads();
    float4 av = make_float4(0.f,0.f,0.f,0.f);
    if (aval) av = *(const float4*)(ap + k0 + akc);
    As[akc+0][ar] = av.x; As[akc+1][ar] = av.y; As[akc+2][ar] = av.z; As[akc+3][ar] = av.w;
    *(float4*)&Bs[bkr][bnc] = *(const float4*)(baU + (size_t)(k0 + bkr)*256 + n0 + bnc);
    __syncthreads();
    INNER8(As, Bs)
  }
  #pragma unroll
  for (int i = 0; i < 8; i++){
    int rr = Mb + ty*8 + i;
    if (rr < TT){
      float4 o0 = {c_[i][0],c_[i][1],c_[i][2],c_[i][3]};
      float4 o1 = {c_[i][4],c_[i][5],c_[i][6],c_[i][7]};
      *(float4*)&T1[(size_t)rr*256 + n0 + tx*8] = o0;
      *(float4*)&T1[(size_t)rr*256 + n0 + tx*8 + 4] = o1;
    }
  }
}

// ---------------- K2b: dvec = enh@ba_Wd + ba_b ; evec = enm@ba_We ----------------
__global__ __launch_bounds__(256) void k_vecs(const float* E, const float* Wd,
    const float* We, const float* bab, float* dvec, float* evec){
  int w = threadIdx.x >> 6, lane = threadIdx.x & 63;
  int t = blockIdx.x*4 + w;
  const float* enh = E + (size_t)t*NE;
  const float* enm = enh + 256;
  float sd = 0.f, se = 0.f;
  for (int l = lane; l < 256; l += 64){ sd += enh[l]*Wd[l]; se += enm[l]*We[l]; }
  for (int o = 1; o < 64; o <<= 1){ sd += __shfl_xor(sd, o, 64); se += __shfl_xor(se, o, 64); }
  if (lane == 0){ dvec[t] = sd + bab[0]; evec[t] = se; }
}

// ---------------- K3a: S[b,h,m] = T1[b,h,:]·enm[b,m,:] + dvec[h] + evec[m] ----------
__global__ __launch_bounds__(256) void k_ns(const float* T1, const float* E,
    const float* dvec, const float* evec, float* S){
  __shared__ float As[8][132];
  __shared__ float Bs[8][132];
  int tid = threadIdx.x, tx = tid & 15, ty = tid >> 4;
  int b = blockIdx.y;
  int tm = blockIdx.x / 5, tn = blockIdx.x - tm*5;
  int Mb = tm*128, n0 = tn*128;
  int ar = tid >> 1, akc = (tid & 1) * 4;
  int hrow = Mb + ar; bool aval = hrow < L1;
  const float* ap = T1 + ((size_t)b*L1 + (aval ? hrow : 0))*256;
  int mrow = n0 + ar; bool bval = mrow < L1;
  const float* bp = E + ((size_t)b*L1 + (bval ? mrow : 0))*NE + 256;
  float c_[8][8] = {};
  for (int k0 = 0; k0 < 256; k0 += 8){
    __syncthreads();
    float4 av = make_float4(0.f,0.f,0.f,0.f);
    float4 bv2 = make_float4(0.f,0.f,0.f,0.f);
    if (aval) av = *(const float4*)(ap + k0 + akc);
    if (bval) bv2 = *(const float4*)(bp + k0 + akc);
    As[akc+0][ar] = av.x; As[akc+1][ar] = av.y; As[akc+2][ar] = av.z; As[akc+3][ar] = av.w;
    Bs[akc+0][ar] = bv2.x; Bs[akc+1][ar] = bv2.y; Bs[akc+2][ar] = bv2.z; Bs[akc+3][ar] = bv2.w;
    __syncthreads();
    INNER8(As, Bs)
  }
  float dr[8], er[8];
  #pragma unroll
  for (int i = 0; i < 8; i++){ int h = Mb + ty*8 + i; dr[i] = (h < L1) ? dvec[b*L1 + h] : 0.f; }
  #pragma unroll
  for (int j = 0; j < 8; j++){ int m = n0 + tx*8 + j; er[j] = (m < L1) ? evec[b*L1 + m] : 0.f; }
  float* Sb = S + (size_t)b*L1*L1;
  #pragma unroll
  for (int i = 0; i < 8; i++){
    int h = Mb + ty*8 + i;
    if (h < L1){
      #pragma unroll
      for (int j = 0; j < 8; j++){
        int m = n0 + tx*8 + j;
        if (m < L1) Sb[(size_t)h*L1 + m] = c_[i][j] + dr[i] + er[j];
      }
    }
  }
}

// --------- K3b: per-column log-softmax(gold) + node_nll + argmax decode -----------
__global__ __launch_bounds__(256) void k_nodecol(const float* S, const int* eh,
    const int* mask, float* out, int* idx){
  int b = blockIdx.y, mt = blockIdx.x;
  __shared__ float msk[L1];
  __shared__ float rM[8][32], rS[8][32], rG[8][32], rB[8][32];
  __shared__ int rH[8][32];
  __shared__ float npart[32];
  int tid = threadIdx.x; int c = tid & 31, r = tid >> 5;
  for (int h = tid; h < L1; h += 256) msk[h] = h ? (float)mask[b*LLEN + h - 1] : 0.f;
  __syncthreads();
  int m = mt*32 + c; bool valid = m < L1; int mc = valid ? m : (L1-1);
  float maskm = msk[mc];
  int gold = 0; if (valid && m) gold = eh[b*LLEN + m - 1];
  const float* Sb = S + (size_t)b*L1*L1;
  float Mx = -3.4e38f, Sm = 0.f, G = 0.f, Bv = -3.4e38f; int Bh = 0;
  for (int h = r; h < L1; h += 8){
    float s = Sb[(size_t)h*L1 + mc];
    float adj = s + ((msk[h] + maskm) > 1.5f ? 0.69314718055994531f : 0.f);
    float nm = fmaxf(Mx, adj);
    Sm = Sm * expf(Mx - nm) + expf(adj - nm);
    Mx = nm;
    if (h == gold) G = adj;
    float dv = (h == m) ? -3.4e38f : (s + (msk[h] > 0.5f ? 0.f : -1e8f));
    if (dv > Bv){ Bv = dv; Bh = h; }
  }
  rM[r][c] = Mx; rS[r][c] = Sm; rG[r][c] = G; rB[r][c] = Bv; rH[r][c] = Bh;
  __syncthreads();
  if (r == 0){
    float M0 = rM[0][c], S0 = rS[0][c], G0 = rG[0][c], B0 = rB[0][c]; int H0 = rH[0][c];
    for (int rr = 1; rr < 8; rr++){
      float m2 = rM[rr][c], s2 = rS[rr][c];
      float nm = fmaxf(M0, m2);
      S0 = S0*expf(M0 - nm) + s2*expf(m2 - nm); M0 = nm;
      G0 += rG[rr][c];
      float b2 = rB[rr][c]; int h2 = rH[rr][c];
      if (b2 > B0 || (b2 == B0 && h2 < H0)){ B0 = b2; H0 = h2; }
    }
    float nll = 0.f;
    if (valid && m >= 1) nll = (M0 + logf(S0)) - G0;
    npart[c] = nll;
    if (valid){
      idx[TT + b*L1 + m] = b*L1 + H0;
      if (m >= 1) out[b*LLEN + m - 1] = (float)H0;
    }
  }
  __syncthreads();
  if (tid == 0){
    float ssum = 0.f;
    for (int i2 = 0; i2 < 32; i2++) ssum += npart[i2];
    atomicAdd(out + 98368, ssum);
  }
}

// --------- K4: label bilinear as big-K MFMA GEMM, P generated on the fly ----------
// v8 (unchanged this round): split-K wave halves, 2 slices/barrier, 130 iters.
__global__ __launch_bounds__(512, 1) void k_label(const float* E, const unsigned short* WtTp,
    const int* idx, const int* labbuf, const float* lblb, float* out){
  __shared__ __align__(16) unsigned char Bst[8*8192];   // [2 halves][4 bufs][8192]
  __shared__ __align__(16) unsigned int xls[256*65];    // 256 tok x 130 bf16, stride 65 u32
  int tid = threadIdx.x;
  int w = tid >> 6, lane = tid & 63, c = lane & 15, q = lane >> 4;
  int wgrp = w & 3, khalf = w >> 2;
  int bx = blockIdx.x;
  bool pred = bx >= 128;
  int q0 = (bx & 127) * 256;        // compact index within pass: q -> (b=q>>9, m=(q&511)+1)
  int ibase = pred ? TT : 0;

  const char* gW = (const char*)WtTp;
  int f = tid;
  int bn = ((f >> 6) << 4) + (f & 15);
  int bkq = (f >> 4) & 3;
  const char* bsrc0 = gW + (size_t)bn*(KP*2) + (size_t)bkq*16;
  unsigned char* BbA = Bst;            // [4][8192] for K-half 0
  unsigned char* BbB = Bst + 4*8192;   // [4][8192] for K-half 1
  auto stage2 = [&](int s){
    __builtin_amdgcn_global_load_lds((gptr_t)(bsrc0 + (size_t)s*64),
        (sptr_t)(BbA + (s & 3)*8192 + f*16), 16, 0, 0);
    __builtin_amdgcn_global_load_lds((gptr_t)(bsrc0 + (size_t)(260 + s)*64),
        (sptr_t)(BbB + (s & 3)*8192 + f*16), 16, 0, 0);
  };
  stage2(0); stage2(1);

  {
    int tok = tid >> 1, half = tid & 1;
    int qq = q0 + tok;
    int trow = (qq >> 9)*L1 + (qq & 511) + 1;
    int g = idx[ibase + trow];
    const float* xr = E + (size_t)g*NE + 512 + half*64;
    unsigned* dstx = &xls[tok*65 + half*32];
    #pragma unroll
    for (int j = 0; j < 16; j++){
      float4 v = *(const float4*)(xr + j*4);
      dstx[2*j]   = cvtpk(v.x, v.y);
      dstx[2*j+1] = cvtpk(v.z, v.w);
    }
  }

  const float *yvb[4], *xvb[4];
  int tokl[4];
  #pragma unroll
  for (int ms = 0; ms < 4; ms++){
    int tl = (wgrp*4 + ms)*16 + c;
    tokl[ms] = tl;
    int qq = q0 + tl;
    int trow = (qq >> 9)*L1 + (qq & 511) + 1;
    int g = idx[ibase + trow];
    yvb[ms] = E + (size_t)trow*NE + 640 + 8*q;   // elm row, this lane's q-offset
    xvb[ms] = E + (size_t)g*NE + 512 + 8*q;      // elh row (gathered)
  }
  f32x4 acc[4][8];
  #pragma unroll
  for (int ms = 0; ms < 4; ms++)
    #pragma unroll
    for (int ns = 0; ns < 8; ns++){ acc[ms][ns][0]=0.f; acc[ms][ns][1]=0.f; acc[ms][ns][2]=0.f; acc[ms][ns][3]=0.f; }

  __syncthreads();   // xls visible; full drain of prologue stages (once)

  const unsigned short* xsh = (const unsigned short*)xls;
  float xs0[4], xs1[4];
  #pragma unroll
  for (int ms = 0; ms < 4; ms++){
    xs0[ms] = bf2f(xsh[tokl[ms]*130]);
    xs1[ms] = bf2f(xsh[tokl[ms]*130 + 1]);
  }

  float yreg[4][8];
  for (int u = 0; u < 130; u++){
    if (u) { asm volatile("s_waitcnt vmcnt(0)" ::: "memory"); }
    __builtin_amdgcn_sched_barrier(0);
    __builtin_amdgcn_s_barrier();
    __builtin_amdgcn_sched_barrier(0);
    if (2*u + 2 < 260){ stage2(2*u + 2); stage2(2*u + 3); }
    int ph = (u >= 65);
    int d0 = 2*u - ph*130;
    if (d0 == 0){
      int e0 = (khalf*2 + ph) * 32;
      #pragma unroll
      for (int ms = 0; ms < 4; ms++){
        float4 v0 = *(const float4*)(yvb[ms] + e0);
        float4 v1 = *(const float4*)(yvb[ms] + e0 + 4);
        yreg[ms][0]=v0.x; yreg[ms][1]=v0.y; yreg[ms][2]=v0.z; yreg[ms][3]=v0.w;
        yreg[ms][4]=v1.x; yreg[ms][5]=v1.y; yreg[ms][6]=v1.z; yreg[ms][7]=v1.w;
      }
    }
    bf16x8 afr0[4], afr1[4];
    if (d0 < 128){
      #pragma unroll
      for (int ms = 0; ms < 4; ms++){
        float a0 = xs0[ms], a1 = xs1[ms];
        union { unsigned u[4]; bf16x8 v; } u0, u1;
        u0.u[0] = cvtpk(a0*yreg[ms][0], a0*yreg[ms][1]);
        u0.u[1] = cvtpk(a0*yreg[ms][2], a0*yreg[ms][3]);
        u0.u[2] = cvtpk(a0*yreg[ms][4], a0*yreg[ms][5]);
        u0.u[3] = cvtpk(a0*yreg[ms][6], a0*yreg[ms][7]);
        u1.u[0] = cvtpk(a1*yreg[ms][0], a1*yreg[ms][1]);
        u1.u[1] = cvtpk(a1*yreg[ms][2], a1*yreg[ms][3]);
        u1.u[2] = cvtpk(a1*yreg[ms][4], a1*yreg[ms][5]);
        u1.u[3] = cvtpk(a1*yreg[ms][6], a1*yreg[ms][7]);
        afr0[ms] = u0.v; afr1[ms] = u1.v;
      }
    } else {
      int e0 = (khalf*2 + ph) * 32;
      #pragma unroll
      for (int ms = 0; ms < 4; ms++){
        float4 u0f = *(const float4*)(xvb[ms] + e0);
        float4 u1f = *(const float4*)(xvb[ms] + e0 + 4);
        union { unsigned u[4]; bf16x8 v; } ux, uy;
        ux.u[0]=cvtpk(u0f.x,u0f.y); ux.u[1]=cvtpk(u0f.z,u0f.w);
        ux.u[2]=cvtpk(u1f.x,u1f.y); ux.u[3]=cvtpk(u1f.z,u1f.w);
        uy.u[0]=cvtpk(yreg[ms][0],yreg[ms][1]); uy.u[1]=cvtpk(yreg[ms][2],yreg[ms][3]);
        uy.u[2]=cvtpk(yreg[ms][4],yreg[ms][5]); uy.u[3]=cvtpk(yreg[ms][6],yreg[ms][7]);
        afr0[ms] = ux.v; afr1[ms] = uy.v;
      }
    }
    {
      int nd0 = 2*(u + 1) - ((u + 1 >= 65) ? 130 : 0);
      if (nd0 >= 128) nd0 = 0;
      #pragma unroll
      for (int ms = 0; ms < 4; ms++){
        xs0[ms] = bf2f(xsh[tokl[ms]*130 + nd0]);
        xs1[ms] = bf2f(xsh[tokl[ms]*130 + nd0 + 1]);
      }
    }
    const char* hb = (const char*)(khalf ? BbB : BbA);
    const char* bs0 = hb + ((2*u) & 3)*8192;
    const char* bs1 = hb + ((2*u + 1) & 3)*8192;
    #pragma unroll
    for (int ns = 0; ns < 8; ns++){
      bf16x8 bfr0 = *(const bf16x8*)(bs0 + ns*1024 + lane*16);
      bf16x8 bfr1 = *(const bf16x8*)(bs1 + ns*1024 + lane*16);
      #pragma unroll
      for (int ms = 0; ms < 4; ms++){
        acc[ms][ns] = __builtin_amdgcn_mfma_f32_16x16x32_bf16(afr0[ms], bfr0, acc[ms][ns], 0, 0, 0);
        acc[ms][ns] = __builtin_amdgcn_mfma_f32_16x16x32_bf16(afr1[ms], bfr1, acc[ms][ns], 0, 0, 0);
      }
    }
  }

  __syncthreads();
  float* cmb = (float*)xls;
  #pragma unroll
  for (int ms = 0; ms < 4; ms++){
    if (khalf == 1){
      #pragma unroll
      for (int ns = 0; ns < 8; ns++)
        *(f32x4*)&cmb[((wgrp*64 + lane)*8 + ((ns + lane) & 7))*4] = acc[ms][ns];
    }
    __syncthreads();
    if (khalf == 0){
      #pragma unroll
      for (int ns = 0; ns < 8; ns++){
        f32x4 t = *(const f32x4*)&cmb[((wgrp*64 + lane)*8 + ((ns + lane) & 7))*4];
        acc[ms][ns][0] += t[0]; acc[ms][ns][1] += t[1];
        acc[ms][ns][2] += t[2]; acc[ms][ns][3] += t[3];
      }
    }
    __syncthreads();
  }
  if (khalf == 1) return;

  float bv[8];
  #pragma unroll
  for (int ns = 0; ns < 8; ns++) bv[ns] = lblb[ns*16 + c];
  float part = 0.f;
  #pragma unroll
  for (int ms = 0; ms < 4; ms++){
    int tb = (wgrp*4 + ms)*16 + 4*q;
    float mx[4] = {-3.4e38f, -3.4e38f, -3.4e38f, -3.4e38f};
    #pragma unroll
    for (int ns = 0; ns < 8; ns++)
      #pragma unroll
      for (int i = 0; i < 4; i++){
        float v = acc[ms][ns][i] + bv[ns];
        mx[i] = fmaxf(mx[i], v);
      }
    #pragma unroll
    for (int o = 1; o < 16; o <<= 1)
      #pragma unroll
      for (int i = 0; i < 4; i++) mx[i] = fmaxf(mx[i], __shfl_xor(mx[i], o, 64));
    if (!pred){
      int lab[4];
      #pragma unroll
      for (int i = 0; i < 4; i++){
        int qq = q0 + tb + i;
        int trow = (qq >> 9)*L1 + (qq & 511) + 1;
        lab[i] = labbuf[trow];
      }
      float se[4] = {0.f,0.f,0.f,0.f}, gp[4] = {0.f,0.f,0.f,0.f};
      #pragma unroll
      for (int ns = 0; ns < 8; ns++)
        #pragma unroll
        for (int i = 0; i < 4; i++){
          float v = acc[ms][ns][i] + bv[ns];
          se[i] += expf(v - mx[i]);
          if (ns*16 + c == lab[i]) gp[i] += v;
        }
      #pragma unroll
      for (int o = 1; o < 16; o <<= 1)
        #pragma unroll
        for (int i = 0; i < 4; i++){ se[i] += __shfl_xor(se[i], o, 64); gp[i] += __shfl_xor(gp[i], o, 64); }
      if (c == 0){
        #pragma unroll
        for (int i = 0; i < 4; i++) part += mx[i] + logf(se[i]) - gp[i];
      }
    } else {
      if (c == 0){
        #pragma unroll
        for (int i = 0; i < 4; i++)
          out[32768 + q0 + tb + i] = mx[i];
      }
    }
  }
  if (!pred){
    for (int o = 1; o < 64; o <<= 1) part += __shfl_xor(part, o, 64);
    if (lane == 0) atomicAdd(out + 98369, part);
  }
}

extern "C" void kernel_launch(void* const* d_in, const int* in_sizes, int n_in,
                              void* d_out, int out_size, void* d_ws, size_t ws_size,
                              hipStream_t stream){
  const float* memory_bank = (const float*)d_in[0];
  const int* edge_heads = (const int*)d_in[1];
  const int* edge_labels = (const int*)d_in[2];
  const int* mask = (const int*)d_in[4];
  const float* sentinel = (const float*)d_in[5];
  const float* W_enh = (const float*)d_in[6];  const float* b_enh = (const float*)d_in[7];
  const float* W_enm = (const float*)d_in[8];  const float* b_enm = (const float*)d_in[9];
  const float* W_elh = (const float*)d_in[10]; const float* b_elh = (const float*)d_in[11];
  const float* W_elm = (const float*)d_in[12]; const float* b_elm = (const float*)d_in[13];
  const float* ba_U = (const float*)d_in[14];  const float* ba_Wd = (const float*)d_in[15];
  const float* ba_We = (const float*)d_in[16]; const float* ba_b = (const float*)d_in[17];
  const float* lbl_U = (const float*)d_in[18]; const float* lbl_Wl = (const float*)d_in[19];
  const float* lbl_Wr = (const float*)d_in[20]; const float* lbl_b = (const float*)d_in[21];
  float* out = (float*)d_out;

  char* wsc = (char*)d_ws;
  size_t o = 0;
  auto alloc = [&](size_t n){ o = (o + 255) & ~(size_t)255; void* pp = wsc + o; o += n; return pp; };
  float* E     = (float*)alloc((size_t)TT*NE*4);
  float* T1    = (float*)alloc((size_t)TT*256*4);
  float* S     = (float*)alloc((size_t)BB*L1*L1*4);
  unsigned short* WH = (unsigned short*)alloc((size_t)NE*KPAD*2);
  unsigned short* WL = (unsigned short*)alloc((size_t)NE*KPAD*2);
  float* bcat  = (float*)alloc((size_t)NE*4);
  unsigned short* WtTp = (unsigned short*)alloc((size_t)128*KP*2);
  float* dvec  = (float*)alloc((size_t)TT*4);
  float* evec  = (float*)alloc((size_t)TT*4);
  int*   idx   = (int*)alloc((size_t)2*TT*4);
  int*   labbuf= (int*)alloc((size_t)TT*4);

  k_init<<<dim3(129), 256, 0, stream>>>(edge_heads, edge_labels, out, idx, labbuf);
  k_wcat<<<dim3(1248), 256, 0, stream>>>(W_enh, b_enh, W_enm, b_enm, W_elh, b_elh, W_elm, b_elm, WH, WL, bcat);
  k_wtt<<<dim3(65, 128), 256, 0, stream>>>(lbl_U, lbl_Wl, lbl_Wr, WtTp);
  k_encm<<<dim3(129, 6), 512, 0, stream>>>(memory_bank, sentinel, WH, WL, bcat, E);
  k_t1<<<dim3(257, 2), 256, 0, stream>>>(E, ba_U, T1);
  k_vecs<<<dim3(8208), 256, 0, stream>>>(E, ba_Wd, ba_We, ba_b, dvec, evec);
  k_ns<<<dim3(25, 64), 256, 0, stream>>>(T1, E, dvec, evec, S);
  k_nodecol<<<dim3(17, 64), 256, 0, stream>>>(S, edge_heads, mask, out, idx);
  k_label<<<dim3(256), 512, 0, stream>>>(E, WtTp, idx, labbuf, lbl_b, out);
}

// Round 8
// 699.859 us; speedup vs baseline: 2.2051x; 1.2004x over previous
//
#include <hip/hip_runtime.h>
#include <hip/hip_bf16.h>

#define BB 64
#define LLEN 512
#define HH 400
#define L1 513
#define TT 32832      // BB*L1
#define NE 768        // enh(256)|enm(256)|elh(128)|elm(128)
#define KP 16640      // 16384 bilinear + 128 Wl + 128 Wr (phase-permuted)
#define PHW 4160      // per-phase k' width: 130 d-slices * 32
#define KPAD 416      // k_encm padded K (400 -> 13 slices of 32)

typedef __attribute__((ext_vector_type(4))) float f32x4;
typedef __attribute__((ext_vector_type(8))) short bf16x8;
typedef unsigned int u32;
typedef __attribute__((address_space(1))) const u32* gptr_t;
typedef __attribute__((address_space(3))) u32* sptr_t;

// round-to-nearest-even f32 -> bf16 (finite inputs)
__device__ inline unsigned short f2bf(float x){
  unsigned u = __float_as_uint(x);
  unsigned r = (u + 0x7fffu + ((u >> 16) & 1u)) >> 16;
  return (unsigned short)r;
}
// packed RNE f32x2 -> bf16x2 in one instruction (lo = a, hi = b)
__device__ inline unsigned cvtpk(float a, float b){
  unsigned r;
  asm("v_cvt_pk_bf16_f32 %0, %1, %2" : "=v"(r) : "v"(a), "v"(b));
  return r;
}
__device__ inline float bf2f(unsigned short h){
  return __uint_as_float(((unsigned)h) << 16);
}

// ---------------- init: labels1 output, gold gather idx, label buf, zero nll ----
__global__ __launch_bounds__(256) void k_init(const int* eh, const int* el, float* out,
                                              int* idx, int* labbuf){
  int t = blockIdx.x*256 + threadIdx.x;
  if (t < TT){
    int b = t / L1, m = t - b*L1;
    int lab = m ? el[b*LLEN + m - 1] : 0;
    int hd  = m ? eh[b*LLEN + m - 1] : 0;
    out[65536 + t] = (float)lab;
    labbuf[t] = lab;
    idx[t] = b*L1 + hd;
  }
  if (blockIdx.x == 0 && threadIdx.x < 2) out[98368 + threadIdx.x] = 0.f;
}

// -------- build split-bf16 encoder weights WH/WL [n=768][k=416] + bcat --------
__global__ __launch_bounds__(256) void k_wcat(const float* Wenh,const float* benh,
    const float* Wenm,const float* benm,const float* Welh,const float* belh,
    const float* Welm,const float* belm, unsigned short* WH, unsigned short* WL,
    float* bcat){
  int g = blockIdx.x*256 + threadIdx.x;
  if (g < NE*KPAD){
    int n = g / KPAD, k = g - n*KPAD;
    float v = 0.f;
    if (k < HH){
      if (n < 256) v = Wenh[k*256 + n];
      else if (n < 512) v = Wenm[k*256 + n - 256];
      else if (n < 640) v = Welh[k*128 + n - 512];
      else v = Welm[k*128 + n - 640];
    }
    unsigned short h = f2bf(v);
    WH[g] = h;
    WL[g] = f2bf(v - bf2f(h));
  }
  if (g < NE){
    float v;
    if (g < 256) v = benh[g];
    else if (g < 512) v = benm[g - 256];
    else if (g < 640) v = belh[g - 512];
    else v = belm[g - 640];
    bcat[g] = v;
  }
}

// -------- build split-bf16 ba_U: UH/UL [n=256][k=256] (ba_U stored [k][n]) --------
__global__ __launch_bounds__(256) void k_wu(const float* baU, unsigned short* UH,
    unsigned short* UL){
  int g = blockIdx.x*256 + threadIdx.x;   // 65536
  int n = g >> 8, k = g & 255;
  float v = baU[k*256 + n];
  unsigned short h = f2bf(v);
  UH[g] = h;
  UL[g] = f2bf(v - bf2f(h));
}

// ------------- build WtTp[n][k'] bf16, K phase-permuted: k' = p*4160 + d*32 + j,
// (p,d,j): d<128 -> U[n][d][32p+j]; d==128 -> Wl[n][32p+j]; d==129 -> Wr[n][32p+j]
__global__ __launch_bounds__(256) void k_wtt(const float* lblU, const float* Wl,
    const float* Wr, unsigned short* WtTp){
  int n = blockIdx.y;
  int kp = blockIdx.x*256 + threadIdx.x;
  if (kp >= KP) return;
  int p = kp / PHW; int q2 = kp - p*PHW; int dd = q2 >> 5; int j = q2 & 31; int e = p*32 + j;
  float v;
  if (dd < 128) v = lblU[(size_t)n*16384 + dd*128 + e];
  else if (dd == 128) v = Wl[n*128 + e];
  else v = Wr[n*128 + e];
  WtTp[(size_t)n*KP + kp] = f2bf(v);
}

// ---- K1: E = elu([sentinel;mb] @ Wcat + bcat) via split-bf16 MFMA ----
__global__ __launch_bounds__(512) void k_encm(const float* mb, const float* sent,
    const unsigned short* WH, const unsigned short* WL, const float* bcat, float* E){
  __shared__ __align__(16) unsigned char Bst[2][2][8192];   // [buf][H/L][8KB]
  int tid = threadIdx.x, w = tid >> 6, lane = tid & 63, c = lane & 15, q = lane >> 4;
  int tb0 = blockIdx.x*256 + w*32;    // wave's 32 tokens
  int n0 = blockIdx.y*128;

  const float* ap[2];
  #pragma unroll
  for (int ms = 0; ms < 2; ms++){
    int row = tb0 + ms*16 + c;
    const float* p = sent;
    if (row < TT){
      int br = row / L1, mr = row - br*L1;
      if (mr) p = mb + (size_t)(br*LLEN + mr - 1)*HH;
    }
    ap[ms] = p;
  }

  int f = tid;
  int bn = ((f >> 6) << 4) + (f & 15);
  int bkq = (f >> 4) & 3;
  const char* srcH = (const char*)WH + (size_t)(n0 + bn)*(KPAD*2) + bkq*16;
  const char* srcL = (const char*)WL + (size_t)(n0 + bn)*(KPAD*2) + bkq*16;
  auto stageB = [&](int s){
    __builtin_amdgcn_global_load_lds((gptr_t)(srcH + (size_t)s*64),
        (sptr_t)(&Bst[s & 1][0][f*16]), 16, 0, 0);
    __builtin_amdgcn_global_load_lds((gptr_t)(srcL + (size_t)s*64),
        (sptr_t)(&Bst[s & 1][1][f*16]), 16, 0, 0);
  };

  float4 a0[2], a1[2];
  auto loadA = [&](int s){
    #pragma unroll
    for (int ms = 0; ms < 2; ms++){
      int k = s*32 + q*8;
      float4 v0 = make_float4(0.f,0.f,0.f,0.f), v1 = v0;
      if (k < HH){ v0 = *(const float4*)(ap[ms] + k); v1 = *(const float4*)(ap[ms] + k + 4); }
      a0[ms] = v0; a1[ms] = v1;
    }
  };
  stageB(0);
  loadA(0);

  f32x4 acc[2][8];
  #pragma unroll
  for (int ms = 0; ms < 2; ms++)
    #pragma unroll
    for (int ns = 0; ns < 8; ns++){ acc[ms][ns][0]=0.f; acc[ms][ns][1]=0.f; acc[ms][ns][2]=0.f; acc[ms][ns][3]=0.f; }

  for (int s = 0; s < 13; s++){
    asm volatile("s_waitcnt vmcnt(0)" ::: "memory");
    __builtin_amdgcn_sched_barrier(0);
    __builtin_amdgcn_s_barrier();
    __builtin_amdgcn_sched_barrier(0);
    if (s + 1 < 13) stageB(s + 1);
    bf16x8 Ah[2], Al[2];
    #pragma unroll
    for (int ms = 0; ms < 2; ms++){
      float v[8] = {a0[ms].x,a0[ms].y,a0[ms].z,a0[ms].w,a1[ms].x,a1[ms].y,a1[ms].z,a1[ms].w};
      union { unsigned u[4]; bf16x8 b; } uh, ul;
      float r[8];
      #pragma unroll
      for (int j = 0; j < 4; j++){
        unsigned h = cvtpk(v[2*j], v[2*j+1]);
        uh.u[j] = h;
        r[2*j]   = v[2*j]   - __uint_as_float((h & 0xffffu) << 16);
        r[2*j+1] = v[2*j+1] - __uint_as_float((h >> 16) << 16);
      }
      #pragma unroll
      for (int j = 0; j < 4; j++) ul.u[j] = cvtpk(r[2*j], r[2*j+1]);
      Ah[ms] = uh.b; Al[ms] = ul.b;
    }
    if (s + 1 < 13) loadA(s + 1);   // prefetch next slice's A under the MFMAs
    const char* bh = (const char*)&Bst[s & 1][0][0];
    const char* bl = (const char*)&Bst[s & 1][1][0];
    #pragma unroll
    for (int ns = 0; ns < 8; ns++){
      bf16x8 BH = *(const bf16x8*)(bh + ns*1024 + lane*16);
      bf16x8 BL = *(const bf16x8*)(bl + ns*1024 + lane*16);
      #pragma unroll
      for (int ms = 0; ms < 2; ms++){
        acc[ms][ns] = __builtin_amdgcn_mfma_f32_16x16x32_bf16(Ah[ms], BH, acc[ms][ns], 0, 0, 0);
        acc[ms][ns] = __builtin_amdgcn_mfma_f32_16x16x32_bf16(Ah[ms], BL, acc[ms][ns], 0, 0, 0);
        acc[ms][ns] = __builtin_amdgcn_mfma_f32_16x16x32_bf16(Al[ms], BH, acc[ms][ns], 0, 0, 0);
      }
    }
  }

  float bvv[8];
  #pragma unroll
  for (int ns = 0; ns < 8; ns++) bvv[ns] = bcat[n0 + ns*16 + c];
  #pragma unroll
  for (int ms = 0; ms < 2; ms++){
    #pragma unroll
    for (int i = 0; i < 4; i++){
      int row = tb0 + ms*16 + 4*q + i;
      if (row < TT){
        #pragma unroll
        for (int ns = 0; ns < 8; ns++){
          float t = acc[ms][ns][i] + bvv[ns];
          E[(size_t)row*NE + n0 + ns*16 + c] = t > 0.f ? t : expm1f(t);
        }
      }
    }
  }
}

// ---- K2 (v10): T1 = enh @ ba_U via split-bf16 MFMA (k_encm structure) ----
__global__ __launch_bounds__(256) void k_t1m(const float* E, const unsigned short* UH,
    const unsigned short* UL, float* T1){
  __shared__ __align__(16) unsigned char Bst[2][2][8192];
  int tid = threadIdx.x, w = tid >> 6, lane = tid & 63, c = lane & 15, q = lane >> 4;
  int tb0 = blockIdx.x*128 + w*32;
  int n0 = blockIdx.y*128;

  const float* ap[2];
  #pragma unroll
  for (int ms = 0; ms < 2; ms++){
    int row = tb0 + ms*16 + c;
    ap[ms] = E + (size_t)(row < TT ? row : 0)*NE;   // enh = E[:,0:256]
  }

  auto stageB = [&](int s){
    #pragma unroll
    for (int i = 0; i < 2; i++){
      int f = i*256 + tid;
      int n = n0 + ((f >> 6) << 4) + (f & 15);
      int kq = (f >> 4) & 3;
      __builtin_amdgcn_global_load_lds((gptr_t)((const char*)UH + (size_t)n*512 + (size_t)s*64 + kq*16),
          (sptr_t)(&Bst[s & 1][0][f*16]), 16, 0, 0);
      __builtin_amdgcn_global_load_lds((gptr_t)((const char*)UL + (size_t)n*512 + (size_t)s*64 + kq*16),
          (sptr_t)(&Bst[s & 1][1][f*16]), 16, 0, 0);
    }
  };

  float4 a0[2], a1[2];
  auto loadA = [&](int s){
    #pragma unroll
    for (int ms = 0; ms < 2; ms++){
      int k = s*32 + q*8;
      a0[ms] = *(const float4*)(ap[ms] + k);
      a1[ms] = *(const float4*)(ap[ms] + k + 4);
    }
  };
  stageB(0);
  loadA(0);

  f32x4 acc[2][8];
  #pragma unroll
  for (int ms = 0; ms < 2; ms++)
    #pragma unroll
    for (int ns = 0; ns < 8; ns++){ acc[ms][ns][0]=0.f; acc[ms][ns][1]=0.f; acc[ms][ns][2]=0.f; acc[ms][ns][3]=0.f; }

  for (int s = 0; s < 8; s++){
    asm volatile("s_waitcnt vmcnt(0)" ::: "memory");
    __builtin_amdgcn_sched_barrier(0);
    __builtin_amdgcn_s_barrier();
    __builtin_amdgcn_sched_barrier(0);
    if (s + 1 < 8) stageB(s + 1);
    bf16x8 Ah[2], Al[2];
    #pragma unroll
    for (int ms = 0; ms < 2; ms++){
      float v[8] = {a0[ms].x,a0[ms].y,a0[ms].z,a0[ms].w,a1[ms].x,a1[ms].y,a1[ms].z,a1[ms].w};
      union { unsigned u[4]; bf16x8 b; } uh, ul;
      float r[8];
      #pragma unroll
      for (int j = 0; j < 4; j++){
        unsigned h = cvtpk(v[2*j], v[2*j+1]);
        uh.u[j] = h;
        r[2*j]   = v[2*j]   - __uint_as_float((h & 0xffffu) << 16);
        r[2*j+1] = v[2*j+1] - __uint_as_float((h >> 16) << 16);
      }
      #pragma unroll
      for (int j = 0; j < 4; j++) ul.u[j] = cvtpk(r[2*j], r[2*j+1]);
      Ah[ms] = uh.b; Al[ms] = ul.b;
    }
    if (s + 1 < 8) loadA(s + 1);
    const char* bh = (const char*)&Bst[s & 1][0][0];
    const char* bl = (const char*)&Bst[s & 1][1][0];
    #pragma unroll
    for (int ns = 0; ns < 8; ns++){
      bf16x8 BH = *(const bf16x8*)(bh + ns*1024 + lane*16);
      bf16x8 BL = *(const bf16x8*)(bl + ns*1024 + lane*16);
      #pragma unroll
      for (int ms = 0; ms < 2; ms++){
        acc[ms][ns] = __builtin_amdgcn_mfma_f32_16x16x32_bf16(Ah[ms], BH, acc[ms][ns], 0, 0, 0);
        acc[ms][ns] = __builtin_amdgcn_mfma_f32_16x16x32_bf16(Ah[ms], BL, acc[ms][ns], 0, 0, 0);
        acc[ms][ns] = __builtin_amdgcn_mfma_f32_16x16x32_bf16(Al[ms], BH, acc[ms][ns], 0, 0, 0);
      }
    }
  }

  #pragma unroll
  for (int ms = 0; ms < 2; ms++){
    #pragma unroll
    for (int i = 0; i < 4; i++){
      int row = tb0 + ms*16 + 4*q + i;
      if (row < TT){
        #pragma unroll
        for (int ns = 0; ns < 8; ns++)
          T1[(size_t)row*256 + n0 + ns*16 + c] = acc[ms][ns][i];
      }
    }
  }
}

// ---------------- K2b: dvec = enh@ba_Wd + ba_b ; evec = enm@ba_We ----------------
__global__ __launch_bounds__(256) void k_vecs(const float* E, const float* Wd,
    const float* We, const float* bab, float* dvec, float* evec){
  int w = threadIdx.x >> 6, lane = threadIdx.x & 63;
  int t = blockIdx.x*4 + w;
  const float* enh = E + (size_t)t*NE;
  const float* enm = enh + 256;
  float sd = 0.f, se = 0.f;
  for (int l = lane; l < 256; l += 64){ sd += enh[l]*Wd[l]; se += enm[l]*We[l]; }
  for (int o = 1; o < 64; o <<= 1){ sd += __shfl_xor(sd, o, 64); se += __shfl_xor(se, o, 64); }
  if (lane == 0){ dvec[t] = sd + bab[0]; evec[t] = se; }
}

// ---- K3a (v10): S[b,h,m] = T1[b,h,:]·enm[b,m,:] + dvec[h] + evec[m], MFMA ----
// B (= enm) split on the fly, staged via ds_write into the chunk layout the
// lane*16 read expects. One barrier per slice; write buf (s+1)&1 || read buf s&1.
__global__ __launch_bounds__(256) void k_nsm(const float* T1, const float* E,
    const float* dvec, const float* evec, float* S){
  __shared__ __align__(16) unsigned char Bst[2][2][8192];
  int tid = threadIdx.x, w = tid >> 6, lane = tid & 63, c = lane & 15, q = lane >> 4;
  int b = blockIdx.y;
  int tm = blockIdx.x / 5, tn = blockIdx.x - tm*5;
  int Mb = tm*128, n0 = tn*128;
  int tb0 = Mb + w*32;

  const float* ap[2];
  #pragma unroll
  for (int ms = 0; ms < 2; ms++){
    int h = tb0 + ms*16 + c;
    int hc = h < L1 ? h : L1 - 1;
    ap[ms] = T1 + ((size_t)b*L1 + hc)*256;
  }

  auto stageB = [&](int s, int buf){
    int k0 = s*32;
    #pragma unroll
    for (int i = 0; i < 2; i++){
      int f = i*256 + tid;
      int mc = n0 + ((f >> 6) << 4) + (f & 15);
      int kq = (f >> 4) & 3;
      int mcc = mc < L1 ? mc : L1 - 1;
      const float* src = E + ((size_t)b*L1 + mcc)*NE + 256 + k0 + kq*8;
      float4 v0 = *(const float4*)src;
      float4 v1 = *(const float4*)(src + 4);
      float v[8] = {v0.x,v0.y,v0.z,v0.w,v1.x,v1.y,v1.z,v1.w};
      union { unsigned u[4]; uint4 u4; } uh, ul;
      float r[8];
      #pragma unroll
      for (int j = 0; j < 4; j++){
        unsigned h = cvtpk(v[2*j], v[2*j+1]);
        uh.u[j] = h;
        r[2*j]   = v[2*j]   - __uint_as_float((h & 0xffffu) << 16);
        r[2*j+1] = v[2*j+1] - __uint_as_float((h >> 16) << 16);
      }
      #pragma unroll
      for (int j = 0; j < 4; j++) ul.u[j] = cvtpk(r[2*j], r[2*j+1]);
      *(uint4*)&Bst[buf][0][f*16] = uh.u4;
      *(uint4*)&Bst[buf][1][f*16] = ul.u4;
    }
  };

  float4 a0[2], a1[2];
  auto loadA = [&](int s){
    #pragma unroll
    for (int ms = 0; ms < 2; ms++){
      int k = s*32 + q*8;
      a0[ms] = *(const float4*)(ap[ms] + k);
      a1[ms] = *(const float4*)(ap[ms] + k + 4);
    }
  };

  stageB(0, 0);
  loadA(0);

  f32x4 acc[2][8];
  #pragma unroll
  for (int ms = 0; ms < 2; ms++)
    #pragma unroll
    for (int ns = 0; ns < 8; ns++){ acc[ms][ns][0]=0.f; acc[ms][ns][1]=0.f; acc[ms][ns][2]=0.f; acc[ms][ns][3]=0.f; }

  __syncthreads();

  for (int s = 0; s < 8; s++){
    if (s + 1 < 8) stageB(s + 1, (s + 1) & 1);
    bf16x8 Ah[2], Al[2];
    #pragma unroll
    for (int ms = 0; ms < 2; ms++){
      float v[8] = {a0[ms].x,a0[ms].y,a0[ms].z,a0[ms].w,a1[ms].x,a1[ms].y,a1[ms].z,a1[ms].w};
      union { unsigned u[4]; bf16x8 b; } uh, ul;
      float r[8];
      #pragma unroll
      for (int j = 0; j < 4; j++){
        unsigned h = cvtpk(v[2*j], v[2*j+1]);
        uh.u[j] = h;
        r[2*j]   = v[2*j]   - __uint_as_float((h & 0xffffu) << 16);
        r[2*j+1] = v[2*j+1] - __uint_as_float((h >> 16) << 16);
      }
      #pragma unroll
      for (int j = 0; j < 4; j++) ul.u[j] = cvtpk(r[2*j], r[2*j+1]);
      Ah[ms] = uh.b; Al[ms] = ul.b;
    }
    if (s + 1 < 8) loadA(s + 1);
    const char* bh = (const char*)&Bst[s & 1][0][0];
    const char* bl = (const char*)&Bst[s & 1][1][0];
    #pragma unroll
    for (int ns = 0; ns < 8; ns++){
      bf16x8 BH = *(const bf16x8*)(bh + ns*1024 + lane*16);
      bf16x8 BL = *(const bf16x8*)(bl + ns*1024 + lane*16);
      #pragma unroll
      for (int ms = 0; ms < 2; ms++){
        acc[ms][ns] = __builtin_amdgcn_mfma_f32_16x16x32_bf16(Ah[ms], BH, acc[ms][ns], 0, 0, 0);
        acc[ms][ns] = __builtin_amdgcn_mfma_f32_16x16x32_bf16(Ah[ms], BL, acc[ms][ns], 0, 0, 0);
        acc[ms][ns] = __builtin_amdgcn_mfma_f32_16x16x32_bf16(Al[ms], BH, acc[ms][ns], 0, 0, 0);
      }
    }
    __syncthreads();
  }

  float er[8];
  #pragma unroll
  for (int ns = 0; ns < 8; ns++){
    int m = n0 + ns*16 + c;
    er[ns] = (m < L1) ? evec[b*L1 + m] : 0.f;
  }
  float* Sb = S + (size_t)b*L1*L1;
  #pragma unroll
  for (int ms = 0; ms < 2; ms++){
    #pragma unroll
    for (int i = 0; i < 4; i++){
      int h = tb0 + ms*16 + 4*q + i;
      if (h < L1){
        float dv = dvec[b*L1 + h];
        #pragma unroll
        for (int ns = 0; ns < 8; ns++){
          int m = n0 + ns*16 + c;
          if (m < L1) Sb[(size_t)h*L1 + m] = acc[ms][ns][i] + dv + er[ns];
        }
      }
    }
  }
}

// --------- K3b: per-column log-softmax(gold) + node_nll + argmax decode -----------
__global__ __launch_bounds__(256) void k_nodecol(const float* S, const int* eh,
    const int* mask, float* out, int* idx){
  int b = blockIdx.y, mt = blockIdx.x;
  __shared__ float msk[L1];
  __shared__ float rM[8][32], rS[8][32], rG[8][32], rB[8][32];
  __shared__ int rH[8][32];
  __shared__ float npart[32];
  int tid = threadIdx.x; int c = tid & 31, r = tid >> 5;
  for (int h = tid; h < L1; h += 256) msk[h] = h ? (float)mask[b*LLEN + h - 1] : 0.f;
  __syncthreads();
  int m = mt*32 + c; bool valid = m < L1; int mc = valid ? m : (L1-1);
  float maskm = msk[mc];
  int gold = 0; if (valid && m) gold = eh[b*LLEN + m - 1];
  const float* Sb = S + (size_t)b*L1*L1;
  float Mx = -3.4e38f, Sm = 0.f, G = 0.f, Bv = -3.4e38f; int Bh = 0;
  for (int h = r; h < L1; h += 8){
    float s = Sb[(size_t)h*L1 + mc];
    float adj = s + ((msk[h] + maskm) > 1.5f ? 0.69314718055994531f : 0.f);
    float nm = fmaxf(Mx, adj);
    Sm = Sm * expf(Mx - nm) + expf(adj - nm);
    Mx = nm;
    if (h == gold) G = adj;
    float dv = (h == m) ? -3.4e38f : (s + (msk[h] > 0.5f ? 0.f : -1e8f));
    if (dv > Bv){ Bv = dv; Bh = h; }
  }
  rM[r][c] = Mx; rS[r][c] = Sm; rG[r][c] = G; rB[r][c] = Bv; rH[r][c] = Bh;
  __syncthreads();
  if (r == 0){
    float M0 = rM[0][c], S0 = rS[0][c], G0 = rG[0][c], B0 = rB[0][c]; int H0 = rH[0][c];
    for (int rr = 1; rr < 8; rr++){
      float m2 = rM[rr][c], s2 = rS[rr][c];
      float nm = fmaxf(M0, m2);
      S0 = S0*expf(M0 - nm) + s2*expf(m2 - nm); M0 = nm;
      G0 += rG[rr][c];
      float b2 = rB[rr][c]; int h2 = rH[rr][c];
      if (b2 > B0 || (b2 == B0 && h2 < H0)){ B0 = b2; H0 = h2; }
    }
    float nll = 0.f;
    if (valid && m >= 1) nll = (M0 + logf(S0)) - G0;
    npart[c] = nll;
    if (valid){
      idx[TT + b*L1 + m] = b*L1 + H0;
      if (m >= 1) out[b*LLEN + m - 1] = (float)H0;
    }
  }
  __syncthreads();
  if (tid == 0){
    float ssum = 0.f;
    for (int i2 = 0; i2 < 32; i2++) ssum += npart[i2];
    atomicAdd(out + 98368, ssum);
  }
}

// --------- K4: label bilinear as big-K MFMA GEMM, P generated on the fly ----------
// v8 (unchanged): split-K wave halves, 2 slices/barrier, 130 iters.
__global__ __launch_bounds__(512, 1) void k_label(const float* E, const unsigned short* WtTp,
    const int* idx, const int* labbuf, const float* lblb, float* out){
  __shared__ __align__(16) unsigned char Bst[8*8192];   // [2 halves][4 bufs][8192]
  __shared__ __align__(16) unsigned int xls[256*65];    // 256 tok x 130 bf16, stride 65 u32
  int tid = threadIdx.x;
  int w = tid >> 6, lane = tid & 63, c = lane & 15, q = lane >> 4;
  int wgrp = w & 3, khalf = w >> 2;
  int bx = blockIdx.x;
  bool pred = bx >= 128;
  int q0 = (bx & 127) * 256;
  int ibase = pred ? TT : 0;

  const char* gW = (const char*)WtTp;
  int f = tid;
  int bn = ((f >> 6) << 4) + (f & 15);
  int bkq = (f >> 4) & 3;
  const char* bsrc0 = gW + (size_t)bn*(KP*2) + (size_t)bkq*16;
  unsigned char* BbA = Bst;
  unsigned char* BbB = Bst + 4*8192;
  auto stage2 = [&](int s){
    __builtin_amdgcn_global_load_lds((gptr_t)(bsrc0 + (size_t)s*64),
        (sptr_t)(BbA + (s & 3)*8192 + f*16), 16, 0, 0);
    __builtin_amdgcn_global_load_lds((gptr_t)(bsrc0 + (size_t)(260 + s)*64),
        (sptr_t)(BbB + (s & 3)*8192 + f*16), 16, 0, 0);
  };
  stage2(0); stage2(1);

  {
    int tok = tid >> 1, half = tid & 1;
    int qq = q0 + tok;
    int trow = (qq >> 9)*L1 + (qq & 511) + 1;
    int g = idx[ibase + trow];
    const float* xr = E + (size_t)g*NE + 512 + half*64;
    unsigned* dstx = &xls[tok*65 + half*32];
    #pragma unroll
    for (int j = 0; j < 16; j++){
      float4 v = *(const float4*)(xr + j*4);
      dstx[2*j]   = cvtpk(v.x, v.y);
      dstx[2*j+1] = cvtpk(v.z, v.w);
    }
  }

  const float *yvb[4], *xvb[4];
  int tokl[4];
  #pragma unroll
  for (int ms = 0; ms < 4; ms++){
    int tl = (wgrp*4 + ms)*16 + c;
    tokl[ms] = tl;
    int qq = q0 + tl;
    int trow = (qq >> 9)*L1 + (qq & 511) + 1;
    int g = idx[ibase + trow];
    yvb[ms] = E + (size_t)trow*NE + 640 + 8*q;
    xvb[ms] = E + (size_t)g*NE + 512 + 8*q;
  }
  f32x4 acc[4][8];
  #pragma unroll
  for (int ms = 0; ms < 4; ms++)
    #pragma unroll
    for (int ns = 0; ns < 8; ns++){ acc[ms][ns][0]=0.f; acc[ms][ns][1]=0.f; acc[ms][ns][2]=0.f; acc[ms][ns][3]=0.f; }

  __syncthreads();

  const unsigned short* xsh = (const unsigned short*)xls;
  float xs0[4], xs1[4];
  #pragma unroll
  for (int ms = 0; ms < 4; ms++){
    xs0[ms] = bf2f(xsh[tokl[ms]*130]);
    xs1[ms] = bf2f(xsh[tokl[ms]*130 + 1]);
  }

  float yreg[4][8];
  for (int u = 0; u < 130; u++){
    if (u) { asm volatile("s_waitcnt vmcnt(0)" ::: "memory"); }
    __builtin_amdgcn_sched_barrier(0);
    __builtin_amdgcn_s_barrier();
    __builtin_amdgcn_sched_barrier(0);
    if (2*u + 2 < 260){ stage2(2*u + 2); stage2(2*u + 3); }
    int ph = (u >= 65);
    int d0 = 2*u - ph*130;
    if (d0 == 0){
      int e0 = (khalf*2 + ph) * 32;
      #pragma unroll
      for (int ms = 0; ms < 4; ms++){
        float4 v0 = *(const float4*)(yvb[ms] + e0);
        float4 v1 = *(const float4*)(yvb[ms] + e0 + 4);
        yreg[ms][0]=v0.x; yreg[ms][1]=v0.y; yreg[ms][2]=v0.z; yreg[ms][3]=v0.w;
        yreg[ms][4]=v1.x; yreg[ms][5]=v1.y; yreg[ms][6]=v1.z; yreg[ms][7]=v1.w;
      }
    }
    bf16x8 afr0[4], afr1[4];
    if (d0 < 128){
      #pragma unroll
      for (int ms = 0; ms < 4; ms++){
        float a0 = xs0[ms], a1 = xs1[ms];
        union { unsigned u[4]; bf16x8 v; } u0, u1;
        u0.u[0] = cvtpk(a0*yreg[ms][0], a0*yreg[ms][1]);
        u0.u[1] = cvtpk(a0*yreg[ms][2], a0*yreg[ms][3]);
        u0.u[2] = cvtpk(a0*yreg[ms][4], a0*yreg[ms][5]);
        u0.u[3] = cvtpk(a0*yreg[ms][6], a0*yreg[ms][7]);
        u1.u[0] = cvtpk(a1*yreg[ms][0], a1*yreg[ms][1]);
        u1.u[1] = cvtpk(a1*yreg[ms][2], a1*yreg[ms][3]);
        u1.u[2] = cvtpk(a1*yreg[ms][4], a1*yreg[ms][5]);
        u1.u[3] = cvtpk(a1*yreg[ms][6], a1*yreg[ms][7]);
        afr0[ms] = u0.v; afr1[ms] = u1.v;
      }
    } else {
      int e0 = (khalf*2 + ph) * 32;
      #pragma unroll
      for (int ms = 0; ms < 4; ms++){
        float4 u0f = *(const float4*)(xvb[ms] + e0);
        float4 u1f = *(const float4*)(xvb[ms] + e0 + 4);
        union { unsigned u[4]; bf16x8 v; } ux, uy;
        ux.u[0]=cvtpk(u0f.x,u0f.y); ux.u[1]=cvtpk(u0f.z,u0f.w);
        ux.u[2]=cvtpk(u1f.x,u1f.y); ux.u[3]=cvtpk(u1f.z,u1f.w);
        uy.u[0]=cvtpk(yreg[ms][0],yreg[ms][1]); uy.u[1]=cvtpk(yreg[ms][2],yreg[ms][3]);
        uy.u[2]=cvtpk(yreg[ms][4],yreg[ms][5]); uy.u[3]=cvtpk(yreg[ms][6],yreg[ms][7]);
        afr0[ms] = ux.v; afr1[ms] = uy.v;
      }
    }
    {
      int nd0 = 2*(u + 1) - ((u + 1 >= 65) ? 130 : 0);
      if (nd0 >= 128) nd0 = 0;
      #pragma unroll
      for (int ms = 0; ms < 4; ms++){
        xs0[ms] = bf2f(xsh[tokl[ms]*130 + nd0]);
        xs1[ms] = bf2f(xsh[tokl[ms]*130 + nd0 + 1]);
      }
    }
    const char* hb = (const char*)(khalf ? BbB : BbA);
    const char* bs0 = hb + ((2*u) & 3)*8192;
    const char* bs1 = hb + ((2*u + 1) & 3)*8192;
    #pragma unroll
    for (int ns = 0; ns < 8; ns++){
      bf16x8 bfr0 = *(const bf16x8*)(bs0 + ns*1024 + lane*16);
      bf16x8 bfr1 = *(const bf16x8*)(bs1 + ns*1024 + lane*16);
      #pragma unroll
      for (int ms = 0; ms < 4; ms++){
        acc[ms][ns] = __builtin_amdgcn_mfma_f32_16x16x32_bf16(afr0[ms], bfr0, acc[ms][ns], 0, 0, 0);
        acc[ms][ns] = __builtin_amdgcn_mfma_f32_16x16x32_bf16(afr1[ms], bfr1, acc[ms][ns], 0, 0, 0);
      }
    }
  }

  __syncthreads();
  float* cmb = (float*)xls;
  #pragma unroll
  for (int ms = 0; ms < 4; ms++){
    if (khalf == 1){
      #pragma unroll
      for (int ns = 0; ns < 8; ns++)
        *(f32x4*)&cmb[((wgrp*64 + lane)*8 + ((ns + lane) & 7))*4] = acc[ms][ns];
    }
    __syncthreads();
    if (khalf == 0){
      #pragma unroll
      for (int ns = 0; ns < 8; ns++){
        f32x4 t = *(const f32x4*)&cmb[((wgrp*64 + lane)*8 + ((ns + lane) & 7))*4];
        acc[ms][ns][0] += t[0]; acc[ms][ns][1] += t[1];
        acc[ms][ns][2] += t[2]; acc[ms][ns][3] += t[3];
      }
    }
    __syncthreads();
  }
  if (khalf == 1) return;

  float bv[8];
  #pragma unroll
  for (int ns = 0; ns < 8; ns++) bv[ns] = lblb[ns*16 + c];
  float part = 0.f;
  #pragma unroll
  for (int ms = 0; ms < 4; ms++){
    int tb = (wgrp*4 + ms)*16 + 4*q;
    float mx[4] = {-3.4e38f, -3.4e38f, -3.4e38f, -3.4e38f};
    #pragma unroll
    for (int ns = 0; ns < 8; ns++)
      #pragma unroll
      for (int i = 0; i < 4; i++){
        float v = acc[ms][ns][i] + bv[ns];
        mx[i] = fmaxf(mx[i], v);
      }
    #pragma unroll
    for (int o = 1; o < 16; o <<= 1)
      #pragma unroll
      for (int i = 0; i < 4; i++) mx[i] = fmaxf(mx[i], __shfl_xor(mx[i], o, 64));
    if (!pred){
      int lab[4];
      #pragma unroll
      for (int i = 0; i < 4; i++){
        int qq = q0 + tb + i;
        int trow = (qq >> 9)*L1 + (qq & 511) + 1;
        lab[i] = labbuf[trow];
      }
      float se[4] = {0.f,0.f,0.f,0.f}, gp[4] = {0.f,0.f,0.f,0.f};
      #pragma unroll
      for (int ns = 0; ns < 8; ns++)
        #pragma unroll
        for (int i = 0; i < 4; i++){
          float v = acc[ms][ns][i] + bv[ns];
          se[i] += expf(v - mx[i]);
          if (ns*16 + c == lab[i]) gp[i] += v;
        }
      #pragma unroll
      for (int o = 1; o < 16; o <<= 1)
        #pragma unroll
        for (int i = 0; i < 4; i++){ se[i] += __shfl_xor(se[i], o, 64); gp[i] += __shfl_xor(gp[i], o, 64); }
      if (c == 0){
        #pragma unroll
        for (int i = 0; i < 4; i++) part += mx[i] + logf(se[i]) - gp[i];
      }
    } else {
      if (c == 0){
        #pragma unroll
        for (int i = 0; i < 4; i++)
          out[32768 + q0 + tb + i] = mx[i];
      }
    }
  }
  if (!pred){
    for (int o = 1; o < 64; o <<= 1) part += __shfl_xor(part, o, 64);
    if (lane == 0) atomicAdd(out + 98369, part);
  }
}

extern "C" void kernel_launch(void* const* d_in, const int* in_sizes, int n_in,
                              void* d_out, int out_size, void* d_ws, size_t ws_size,
                              hipStream_t stream){
  const float* memory_bank = (const float*)d_in[0];
  const int* edge_heads = (const int*)d_in[1];
  const int* edge_labels = (const int*)d_in[2];
  const int* mask = (const int*)d_in[4];
  const float* sentinel = (const float*)d_in[5];
  const float* W_enh = (const float*)d_in[6];  const float* b_enh = (const float*)d_in[7];
  const float* W_enm = (const float*)d_in[8];  const float* b_enm = (const float*)d_in[9];
  const float* W_elh = (const float*)d_in[10]; const float* b_elh = (const float*)d_in[11];
  const float* W_elm = (const float*)d_in[12]; const float* b_elm = (const float*)d_in[13];
  const float* ba_U = (const float*)d_in[14];  const float* ba_Wd = (const float*)d_in[15];
  const float* ba_We = (const float*)d_in[16]; const float* ba_b = (const float*)d_in[17];
  const float* lbl_U = (const float*)d_in[18]; const float* lbl_Wl = (const float*)d_in[19];
  const float* lbl_Wr = (const float*)d_in[20]; const float* lbl_b = (const float*)d_in[21];
  float* out = (float*)d_out;

  char* wsc = (char*)d_ws;
  size_t o = 0;
  auto alloc = [&](size_t n){ o = (o + 255) & ~(size_t)255; void* pp = wsc + o; o += n; return pp; };
  float* E     = (float*)alloc((size_t)TT*NE*4);
  float* T1    = (float*)alloc((size_t)TT*256*4);
  float* S     = (float*)alloc((size_t)BB*L1*L1*4);
  unsigned short* WH = (unsigned short*)alloc((size_t)NE*KPAD*2);
  unsigned short* WL = (unsigned short*)alloc((size_t)NE*KPAD*2);
  unsigned short* UH = (unsigned short*)alloc((size_t)256*256*2);
  unsigned short* UL = (unsigned short*)alloc((size_t)256*256*2);
  float* bcat  = (float*)alloc((size_t)NE*4);
  unsigned short* WtTp = (unsigned short*)alloc((size_t)128*KP*2);
  float* dvec  = (float*)alloc((size_t)TT*4);
  float* evec  = (float*)alloc((size_t)TT*4);
  int*   idx   = (int*)alloc((size_t)2*TT*4);
  int*   labbuf= (int*)alloc((size_t)TT*4);

  k_init<<<dim3(129), 256, 0, stream>>>(edge_heads, edge_labels, out, idx, labbuf);
  k_wcat<<<dim3(1248), 256, 0, stream>>>(W_enh, b_enh, W_enm, b_enm, W_elh, b_elh, W_elm, b_elm, WH, WL, bcat);
  k_wu<<<dim3(256), 256, 0, stream>>>(ba_U, UH, UL);
  k_wtt<<<dim3(65, 128), 256, 0, stream>>>(lbl_U, lbl_Wl, lbl_Wr, WtTp);
  k_encm<<<dim3(129, 6), 512, 0, stream>>>(memory_bank, sentinel, WH, WL, bcat, E);
  k_t1m<<<dim3(257, 2), 256, 0, stream>>>(E, UH, UL, T1);
  k_vecs<<<dim3(8208), 256, 0, stream>>>(E, ba_Wd, ba_We, ba_b, dvec, evec);
  k_nsm<<<dim3(25, 64), 256, 0, stream>>>(T1, E, dvec, evec, S);
  k_nodecol<<<dim3(17, 64), 256, 0, stream>>>(S, edge_heads, mask, out, idx);
  k_label<<<dim3(256), 512, 0, stream>>>(E, WtTp, idx, labbuf, lbl_b, out);
}